// Round 5
// baseline (125.997 us; speedup 1.0000x reference)
//
#include <hip/hip_runtime.h>
#include <hip/hip_bf16.h>

// ---------------- helpers ----------------

// swizzle for 4096-amp f32x2 LDS tile (qstep_a0): XOR low 4 bits with bits 4-7
#define SWZA(i) ((i) ^ (((i) >> 4) & 15))
// swizzle for 4096-entry b32 LDS tile (qstep_a1): XOR low 6 bits with bits 6-11
#define SWZB(i) ((i) ^ (((i) >> 6) & 63))

__device__ __forceinline__ void gate1q(float2& a0, float2& a1, const float* u) {
    // u: u00r,u00i,u01r,u01i,u10r,u10i,u11r,u11i ; new = U * [a0;a1]
    float n0r = u[0]*a0.x - u[1]*a0.y + u[2]*a1.x - u[3]*a1.y;
    float n0i = u[0]*a0.y + u[1]*a0.x + u[2]*a1.y + u[3]*a1.x;
    float n1r = u[4]*a0.x - u[5]*a0.y + u[6]*a1.x - u[7]*a1.y;
    float n1i = u[4]*a0.y + u[5]*a0.x + u[6]*a1.y + u[7]*a1.x;
    a0.x = n0r; a0.y = n0i; a1.x = n1r; a1.y = n1i;
}

__device__ __forceinline__ void crx_pair(float2& a0, float2& a1, float c, float s) {
    // RX on the (a0,a1) pair: n0 = c*a0 - i*s*a1 ; n1 = -i*s*a0 + c*a1
    float n0r = c*a0.x + s*a1.y;
    float n0i = c*a0.y - s*a1.x;
    float n1r = c*a1.x + s*a0.y;
    float n1i = c*a1.y - s*a0.x;
    a0.x = n0r; a0.y = n0i; a1.x = n1r; a1.y = n1i;
}

template<int K, int W>
__device__ __forceinline__ void apply1q_win(float2* a, const float* u) {
    #pragma unroll
    for (int m = 0; m < W / 2; ++m) {
        const int j0 = ((m >> K) << (K + 1)) | (m & ((1 << K) - 1));
        gate1q(a[j0], a[j0 | (1 << K)], u);
    }
}

template<int KC, int KT, int W>
__device__ __forceinline__ void crx_win(float2* a, float c, float s) {
    #pragma unroll
    for (int j = 0; j < W; ++j) {
        if ((j & (1 << KC)) != 0 && (j & (1 << KT)) == 0)
            crx_pair(a[j], a[j | (1 << KT)], c, s);
    }
}

__device__ __forceinline__ void loadU(const float* __restrict__ src, float* u) {
    #pragma unroll
    for (int k = 0; k < 8; ++k) u[k] = src[k];
}

// bf16x2 pack/unpack (RNE)
__device__ __forceinline__ unsigned bf2pack(float x, float y) {
    unsigned ux = __float_as_uint(x); ux = (ux + 0x7FFFu + ((ux >> 16) & 1u)) >> 16;
    unsigned uy = __float_as_uint(y); uy = (uy + 0x7FFFu + ((uy >> 16) & 1u)) >> 16;
    return ux | (uy << 16);
}
__device__ __forceinline__ float2 bf2unpack(unsigned v) {
    return make_float2(__uint_as_float(v << 16), __uint_as_float(v & 0xFFFF0000u));
}

// ---------------- kernel 1: adaptive pool ----------------
__global__ __launch_bounds__(256) void pool_kernel(const float* __restrict__ x,
                                                   float* __restrict__ p) {
    int blk = blockIdx.x;            // b*32 + j
    int b = blk >> 5, j = blk & 31;
    int c = j >> 4, dd = (j >> 2) & 3, hh = j & 3;
    const float4* xb = (const float4*)(x + (((size_t)(b * 2 + c) * 16 + dd * 4) << 12)
                                         + (size_t)hh * 1024);
    int tid = threadIdx.x;
    float sum = 0.f;
    #pragma unroll
    for (int k = 0; k < 4; ++k) {
        int f = k * 256 + tid;
        int r = f >> 4, col = f & 15;
        int off = (r >> 4) * 1024 + (r & 15) * 16 + col;
        float4 v = xb[off];
        sum += v.x + v.y + v.z + v.w;
    }
    #pragma unroll
    for (int o = 1; o < 64; o <<= 1) sum += __shfl_xor(sum, o);
    __shared__ float red[4];
    if ((tid & 63) == 0) red[tid >> 6] = sum;
    __syncthreads();
    if (tid == 0) p[blk] = (red[0] + red[1] + red[2] + red[3]) * (1.0f / 4096.0f);
}

// ---------------- kernel 2: feats + gate precompute + W0 (layer-0 B as 32x2) --------
__global__ __launch_bounds__(64) void feats_kernel(const float* __restrict__ p,
                                                   const float* __restrict__ cw,
                                                   const float* __restrict__ cb,
                                                   const float* __restrict__ rot1,
                                                   const float* __restrict__ crx1,
                                                   const float* __restrict__ rot2,
                                                   const float* __restrict__ crx2,
                                                   float* __restrict__ Uws,
                                                   float* __restrict__ crxcs,
                                                   float* __restrict__ ev,
                                                   float* __restrict__ w0f) {
    int b = blockIdx.x, tid = threadIdx.x;
    __shared__ float pp[32];
    __shared__ float uB[4][8];      // layer-0 U12..U15 for this batch
    if (tid < 32) pp[tid] = p[b * 32 + tid];
    __syncthreads();
    if (tid >= 16 && tid < 32) ev[b * 16 + (tid - 16)] = 0.f;
    if (tid < 16) {
        int q = tid;
        float f = cb[q];
        #pragma unroll
        for (int jj = 0; jj < 32; ++jj) f += pp[jj] * cw[q * 32 + jj];
        float cr = cosf(0.5f * f), sr = sinf(0.5f * f);
        #pragma unroll
        for (int l = 0; l < 2; ++l) {
            const float* rw = (l == 0 ? rot1 : rot2) + q * 3;
            float phi = rw[0], th = rw[1], om = rw[2];
            float ct = cosf(0.5f * th), st = sinf(0.5f * th);
            float aa = 0.5f * (phi + om), dd = 0.5f * (phi - om);
            float ca = cosf(aa), sa = sinf(aa), cd = cosf(dd), sd = sinf(dd);
            float R00r =  ct * ca, R00i = -ct * sa;
            float R01r = -st * cd, R01i = -st * sd;
            float R10r =  st * cd, R10i = -st * sd;
            float R11r =  ct * ca, R11i =  ct * sa;
            float u0 = cr * R00r + sr * R01i;
            float u1 = cr * R00i - sr * R01r;
            float u2 = cr * R01r + sr * R00i;
            float u3 = cr * R01i - sr * R00r;
            float u4 = cr * R10r + sr * R11i;
            float u5 = cr * R10i - sr * R11r;
            float u6 = cr * R11r + sr * R10i;
            float u7 = cr * R11i - sr * R10r;
            float* dst = Uws + ((size_t)(l * 128 + b) * 16 + q) * 8;
            dst[0] = u0; dst[1] = u1; dst[2] = u2; dst[3] = u3;
            dst[4] = u4; dst[5] = u5; dst[6] = u6; dst[7] = u7;
            if (l == 0 && q >= 12) {
                float* ub = uB[q - 12];
                ub[0] = u0; ub[1] = u1; ub[2] = u2; ub[3] = u3;
                ub[4] = u4; ub[5] = u5; ub[6] = u6; ub[7] = u7;
            }
            if (b == 0) {
                float th2 = (l == 0 ? crx1 : crx2)[q];
                crxcs[(l * 16 + q) * 2 + 0] = cosf(0.5f * th2);
                crxcs[(l * 16 + q) * 2 + 1] = sinf(0.5f * th2);
            }
        }
    }
    __syncthreads();
    // W0[b][m][j] = (layer-0 U12..U15 + CRX(11,12)..(14,15)) applied to e_j on the
    // 5-qubit window (bit k = qubit 11+k), restricted to input bits 12..15 = 0.
    if (tid >= 32 && tid < 34) {
        int j = tid - 32;
        float2 w[32];
        #pragma unroll
        for (int m = 0; m < 32; ++m) w[m] = make_float2(0.f, 0.f);
        w[j] = make_float2(1.f, 0.f);
        apply1q_win<1, 32>(w, uB[0]);   // U12
        apply1q_win<2, 32>(w, uB[1]);   // U13
        apply1q_win<3, 32>(w, uB[2]);   // U14
        apply1q_win<4, 32>(w, uB[3]);   // U15
        crx_win<0, 1, 32>(w, cosf(0.5f * crx1[11]), sinf(0.5f * crx1[11]));  // CRX(11,12)
        crx_win<1, 2, 32>(w, cosf(0.5f * crx1[12]), sinf(0.5f * crx1[12]));  // CRX(12,13)
        crx_win<2, 3, 32>(w, cosf(0.5f * crx1[13]), sinf(0.5f * crx1[13]));  // CRX(13,14)
        crx_win<3, 4, 32>(w, cosf(0.5f * crx1[14]), sinf(0.5f * crx1[14]));  // CRX(14,15)
        #pragma unroll
        for (int m = 0; m < 32; ++m) {
            float* d = w0f + ((size_t)(b * 32 + m) * 2 + j) * 2;
            d[0] = w[m].x; d[1] = w[m].y;
        }
    }
}

// ---------------- kernel 3: layer-0 pass A -> 4096-amp seed per batch ----------------
// grid = 128 ; 256 threads ; applies layer-0 U0..U11 + CRX(0,1)..(10,11) to e_0
__global__ __launch_bounds__(256) void qstep_a0(const float* __restrict__ Uws,
                                                const float* __restrict__ crxcs,
                                                float2* __restrict__ seed) {
    __shared__ float2 lds[4096];
    int tid = threadIdx.x;
    int b = blockIdx.x;

    #pragma unroll
    for (int j = 0; j < 16; ++j) lds[SWZA(j * 256 + tid)] = make_float2(0.f, 0.f);
    if (tid == 0) lds[SWZA(0)] = make_float2(1.f, 0.f);
    __syncthreads();

    const float* Ub = Uws + (size_t)b * 128;       // layer 0
    const float* cs = crxcs;                       // layer 0
    float2 a[16];
    float u[8];

    // SR1: bits 0..3
    {
        #pragma unroll
        for (int j = 0; j < 16; ++j) a[j] = lds[SWZA((tid << 4) | j)];
        loadU(Ub + 0 * 8, u);  apply1q_win<0, 16>(a, u);
        loadU(Ub + 1 * 8, u);  apply1q_win<1, 16>(a, u);
        loadU(Ub + 2 * 8, u);  apply1q_win<2, 16>(a, u);
        loadU(Ub + 3 * 8, u);  apply1q_win<3, 16>(a, u);
        crx_win<0, 1, 16>(a, cs[0], cs[1]);
        crx_win<1, 2, 16>(a, cs[2], cs[3]);
        crx_win<2, 3, 16>(a, cs[4], cs[5]);
        #pragma unroll
        for (int j = 0; j < 16; ++j) lds[SWZA((tid << 4) | j)] = a[j];
    }
    __syncthreads();

    // SR2: bits 3..6
    {
        int lo = tid & 7, hi = (tid >> 3) << 7;
        #pragma unroll
        for (int j = 0; j < 16; ++j) a[j] = lds[SWZA(lo | (j << 3) | hi)];
        loadU(Ub + 4 * 8, u);  apply1q_win<1, 16>(a, u);
        loadU(Ub + 5 * 8, u);  apply1q_win<2, 16>(a, u);
        loadU(Ub + 6 * 8, u);  apply1q_win<3, 16>(a, u);
        crx_win<0, 1, 16>(a, cs[6],  cs[7]);
        crx_win<1, 2, 16>(a, cs[8],  cs[9]);
        crx_win<2, 3, 16>(a, cs[10], cs[11]);
        #pragma unroll
        for (int j = 0; j < 16; ++j) lds[SWZA(lo | (j << 3) | hi)] = a[j];
    }
    __syncthreads();

    // SR3: bits 6..9
    {
        int lo = tid & 63, hi = (tid >> 6) << 10;
        #pragma unroll
        for (int j = 0; j < 16; ++j) a[j] = lds[SWZA(lo | (j << 6) | hi)];
        loadU(Ub + 7 * 8, u);  apply1q_win<1, 16>(a, u);
        loadU(Ub + 8 * 8, u);  apply1q_win<2, 16>(a, u);
        loadU(Ub + 9 * 8, u);  apply1q_win<3, 16>(a, u);
        crx_win<0, 1, 16>(a, cs[12], cs[13]);
        crx_win<1, 2, 16>(a, cs[14], cs[15]);
        crx_win<2, 3, 16>(a, cs[16], cs[17]);
        #pragma unroll
        for (int j = 0; j < 16; ++j) lds[SWZA(lo | (j << 6) | hi)] = a[j];
    }
    __syncthreads();

    // SR4: bits 8..11 ; store directly from regs (idx = tid | (j<<8))
    {
        #pragma unroll
        for (int j = 0; j < 16; ++j) a[j] = lds[SWZA(tid | (j << 8))];
        loadU(Ub + 10 * 8, u);  apply1q_win<2, 16>(a, u);
        loadU(Ub + 11 * 8, u);  apply1q_win<3, 16>(a, u);
        crx_win<1, 2, 16>(a, cs[18], cs[19]);
        crx_win<2, 3, 16>(a, cs[20], cs[21]);
        #pragma unroll
        for (int j = 0; j < 16; ++j) seed[((size_t)b << 12) + (j << 8) + tid] = a[j];
    }
}

// ---------------- kernel 4: layer-1 pass A, 128 threads, 32 amps/thread --------------
// grid = 2048 (b = blk>>4, chunk = blk&15) ; ***128 threads*** ; LDS = 16 KB (bf16)
// Round layouts (i = amp index bits 0..11; tid bit 6 = i bit 11 in R1):
//   R1: reg = bits 0-4,  i = (tid<<5)|r      -> W0+CRX15_0, U0-U4, CRX(0,1)..(3,4)
//   R2: reg = bits 4-8,  i = (tid&15)|(r<<4)|((tid>>4)<<9)
//                                            -> U5-U8, CRX(4,5)..(7,8)
//   R3: reg = bits 7-11, i = (tid&127)|(r<<7) -> U9-U11, CRX(8,9)..(10,11), store bf16
__global__ __launch_bounds__(128, 4) void qstep_a1(const float* __restrict__ Uws,
                                                   const float* __restrict__ crxcs,
                                                   const float* __restrict__ w0f,
                                                   const float2* __restrict__ seed,
                                                   unsigned* __restrict__ sbf) {
    __shared__ unsigned lds[4096];
    int tid = threadIdx.x;
    int b = blockIdx.x >> 4, chunk = blockIdx.x & 15;

    // ---- fused layer-0 pass B: m = output idx bits 11..15
    int m = (chunk << 1) | ((tid >> 6) & 1);
    const float* wr = w0f + (size_t)(b * 32 + m) * 4;
    float w0r = wr[0], w0i = wr[1], w1r = wr[2], w1i = wr[3];

    // seed: t = ((tid&63)<<5) | r ; columns j=0 at [t], j=1 at [2048+t]
    const float4* s0 = (const float4*)(seed + ((size_t)b << 12) + ((tid & 63) << 5));
    const float4* s1 = (const float4*)(seed + ((size_t)b << 12) + 2048 + ((tid & 63) << 5));

    float2 a[32];
    {
        float c0 = crxcs[30], sc0 = crxcs[31];   // layer-0 CRX(15,0)
        bool hicrx = (chunk >= 8);               // output bit 15 set -> control active
        #pragma unroll
        for (int rp = 0; rp < 16; ++rp) {
            float4 v = s0[rp];
            float4 w = s1[rp];
            float v0ex, v0ey, v0ox, v0oy, v1ex, v1ey, v1ox, v1oy;
            if (hicrx) {
                v0ex = c0*v.x + sc0*v.w; v0ey = c0*v.y - sc0*v.z;
                v0ox = c0*v.z + sc0*v.y; v0oy = c0*v.w - sc0*v.x;
                v1ex = c0*w.x + sc0*w.w; v1ey = c0*w.y - sc0*w.z;
                v1ox = c0*w.z + sc0*w.y; v1oy = c0*w.w - sc0*w.x;
            } else {
                v0ex = v.x; v0ey = v.y; v0ox = v.z; v0oy = v.w;
                v1ex = w.x; v1ey = w.y; v1ox = w.z; v1oy = w.w;
            }
            a[2*rp].x   = w0r*v0ex - w0i*v0ey + w1r*v1ex - w1i*v1ey;
            a[2*rp].y   = w0r*v0ey + w0i*v0ex + w1r*v1ey + w1i*v1ex;
            a[2*rp+1].x = w0r*v0ox - w0i*v0oy + w1r*v1ox - w1i*v1oy;
            a[2*rp+1].y = w0r*v0oy + w0i*v0ox + w1r*v1oy + w1i*v1ox;
        }
    }

    const float* Ub = Uws + (size_t)(128 + b) * 128;   // layer 1
    const float* cs = crxcs + 32;                      // layer 1
    float u[8];

    // ---- R1: reg window bits 0-4
    loadU(Ub + 0 * 8, u);  apply1q_win<0, 32>(a, u);
    loadU(Ub + 1 * 8, u);  apply1q_win<1, 32>(a, u);
    loadU(Ub + 2 * 8, u);  apply1q_win<2, 32>(a, u);
    loadU(Ub + 3 * 8, u);  apply1q_win<3, 32>(a, u);
    loadU(Ub + 4 * 8, u);  apply1q_win<4, 32>(a, u);
    crx_win<0, 1, 32>(a, cs[0], cs[1]);    // CRX(0,1)
    crx_win<1, 2, 32>(a, cs[2], cs[3]);    // CRX(1,2)
    crx_win<2, 3, 32>(a, cs[4], cs[5]);    // CRX(2,3)
    crx_win<3, 4, 32>(a, cs[6], cs[7]);    // CRX(3,4)
    #pragma unroll
    for (int r = 0; r < 32; ++r) lds[SWZB((tid << 5) | r)] = bf2pack(a[r].x, a[r].y);
    __syncthreads();

    // ---- R2: reg window bits 4-8
    {
        int lo = tid & 15, hi = (tid >> 4) << 9;
        #pragma unroll
        for (int r = 0; r < 32; ++r) a[r] = bf2unpack(lds[SWZB(lo | (r << 4) | hi)]);
        loadU(Ub + 5 * 8, u);  apply1q_win<1, 32>(a, u);   // U5
        loadU(Ub + 6 * 8, u);  apply1q_win<2, 32>(a, u);   // U6
        loadU(Ub + 7 * 8, u);  apply1q_win<3, 32>(a, u);   // U7
        loadU(Ub + 8 * 8, u);  apply1q_win<4, 32>(a, u);   // U8
        crx_win<0, 1, 32>(a, cs[8],  cs[9]);   // CRX(4,5)
        crx_win<1, 2, 32>(a, cs[10], cs[11]);  // CRX(5,6)
        crx_win<2, 3, 32>(a, cs[12], cs[13]);  // CRX(6,7)
        crx_win<3, 4, 32>(a, cs[14], cs[15]);  // CRX(7,8)
        #pragma unroll
        for (int r = 0; r < 32; ++r) lds[SWZB(lo | (r << 4) | hi)] = bf2pack(a[r].x, a[r].y);
    }
    __syncthreads();

    // ---- R3: reg window bits 7-11 ; store bf16 to global
    {
        int lo = tid & 127;
        #pragma unroll
        for (int r = 0; r < 32; ++r) a[r] = bf2unpack(lds[SWZB(lo | (r << 7))]);
        loadU(Ub + 9 * 8, u);   apply1q_win<2, 32>(a, u);  // U9  (bit 9 = reg bit 2)
        loadU(Ub + 10 * 8, u);  apply1q_win<3, 32>(a, u);  // U10
        loadU(Ub + 11 * 8, u);  apply1q_win<4, 32>(a, u);  // U11
        crx_win<1, 2, 32>(a, cs[16], cs[17]);  // CRX(8,9)
        crx_win<2, 3, 32>(a, cs[18], cs[19]);  // CRX(9,10)
        crx_win<3, 4, 32>(a, cs[20], cs[21]);  // CRX(10,11)
        unsigned* dst = sbf + ((size_t)b << 16) + ((size_t)chunk << 12) + lo;
        #pragma unroll
        for (int r = 0; r < 32; ++r) dst[r << 7] = bf2pack(a[r].x, a[r].y);
    }
}

// ---------------- kernel 5: layer-1 pass B + EV reduce (bf16 state in) ---------------
// grid: 1024 (b = blk>>3, part = blk&7) ; 256 threads ; t = idx bits 0..10
__global__ __launch_bounds__(256) void qstep_b1(const float* __restrict__ Uws,
                                                const float* __restrict__ crxcs,
                                                const unsigned* __restrict__ sbf,
                                                float* __restrict__ ev) {
    int tid = threadIdx.x;
    int b = blockIdx.x >> 3, part = blockIdx.x & 7;
    int t = part * 256 + tid;
    size_t base = ((size_t)b << 16) + t;
    float2 a[32];
    #pragma unroll
    for (int j = 0; j < 32; ++j) a[j] = bf2unpack(sbf[base + ((size_t)j << 11)]);

    const float* Ub = Uws + (size_t)(128 + b) * 128;
    const float* cs = crxcs + 32;
    float u[8];
    loadU(Ub + 12 * 8, u);  apply1q_win<1, 32>(a, u);
    loadU(Ub + 13 * 8, u);  apply1q_win<2, 32>(a, u);
    loadU(Ub + 14 * 8, u);  apply1q_win<3, 32>(a, u);
    loadU(Ub + 15 * 8, u);  apply1q_win<4, 32>(a, u);
    crx_win<0, 1, 32>(a, cs[22], cs[23]);
    crx_win<1, 2, 32>(a, cs[24], cs[25]);
    crx_win<2, 3, 32>(a, cs[26], cs[27]);
    crx_win<3, 4, 32>(a, cs[28], cs[29]);
    {   // CRX(15,0): control = j bit 4, target = idx bit 0 = lane bit 0
        float c = cs[30], s = cs[31];
        #pragma unroll
        for (int j = 16; j < 32; ++j) {
            float pr = __shfl_xor(a[j].x, 1);
            float pi = __shfl_xor(a[j].y, 1);
            float nr = c * a[j].x + s * pi;
            float ni = c * a[j].y - s * pr;
            a[j].x = nr; a[j].y = ni;
        }
    }

    float P = 0.f, S0 = 0.f, S1 = 0.f, S2 = 0.f, S3 = 0.f, S4 = 0.f;
    #pragma unroll
    for (int j = 0; j < 32; ++j) {
        float pr = a[j].x * a[j].x + a[j].y * a[j].y;
        P += pr;
        S0 += (j & 1)  ? -pr : pr;
        S1 += (j & 2)  ? -pr : pr;
        S2 += (j & 4)  ? -pr : pr;
        S3 += (j & 8)  ? -pr : pr;
        S4 += (j & 16) ? -pr : pr;
    }
    float evq[16];
    #pragma unroll
    for (int q = 0; q < 11; ++q) evq[q] = ((t >> q) & 1) ? -P : P;
    evq[11] = S0; evq[12] = S1; evq[13] = S2; evq[14] = S3; evq[15] = S4;
    #pragma unroll
    for (int q = 0; q < 16; ++q) {
        float v = evq[q];
        #pragma unroll
        for (int o = 32; o >= 1; o >>= 1) v += __shfl_xor(v, o);
        evq[q] = v;
    }
    __shared__ float red[4][16];
    int wave = tid >> 6, lane = tid & 63;
    if (lane == 0) {
        #pragma unroll
        for (int q = 0; q < 16; ++q) red[wave][q] = evq[q];
    }
    __syncthreads();
    if (tid < 16) {
        float v = red[0][tid] + red[1][tid] + red[2][tid] + red[3][tid];
        atomicAdd(&ev[b * 16 + tid], v);
    }
}

// ---------------- kernel 6: head + log_softmax ----------------
__global__ __launch_bounds__(128) void head_kernel(const float* __restrict__ ev,
                                                   const float* __restrict__ fcw,
                                                   const float* __restrict__ fcb,
                                                   float* __restrict__ out) {
    int b = threadIdx.x;
    if (b >= 128) return;
    float e[16];
    #pragma unroll
    for (int q = 0; q < 16; ++q) e[q] = ev[b * 16 + q];
    float lg[16];
    float mx = -1e30f;
    #pragma unroll
    for (int c = 0; c < 16; ++c) {
        float v = fcb[c];
        #pragma unroll
        for (int q = 0; q < 16; ++q) v += e[q] * fcw[c * 16 + q];
        lg[c] = v;
        mx = fmaxf(mx, v);
    }
    float se = 0.f;
    #pragma unroll
    for (int c = 0; c < 16; ++c) se += expf(lg[c] - mx);
    float lse = mx + logf(se);
    #pragma unroll
    for (int c = 0; c < 16; ++c) out[b * 16 + c] = lg[c] - lse;
}

// ---------------- launch ----------------
extern "C" void kernel_launch(void* const* d_in, const int* in_sizes, int n_in,
                              void* d_out, int out_size, void* d_ws, size_t ws_size,
                              hipStream_t stream) {
    const float* x    = (const float*)d_in[0];
    const float* cw   = (const float*)d_in[1];
    const float* cb   = (const float*)d_in[2];
    const float* rot1 = (const float*)d_in[3];
    const float* crx1 = (const float*)d_in[4];
    const float* rot2 = (const float*)d_in[5];
    const float* crx2 = (const float*)d_in[6];
    const float* fcw  = (const float*)d_in[7];
    const float* fcb  = (const float*)d_in[8];

    float* ws    = (float*)d_ws;
    float* p     = ws;                         // 4096
    float* U     = ws + 4096;                  // 32768 -> ends 36864
    float* crxcs = ws + 36864;                 // 64
    float* ev    = ws + 36928;                 // 2048 -> ends 38976
    float* w0f   = ws + 40960;                 // 16384 -> ends 57344
    float2* seed = (float2*)(ws + 65536);      // 128*4096 float2 = 4 MiB
    unsigned* sbf = (unsigned*)(ws + 1114112); // 128*65536 uint = 32 MiB

    pool_kernel<<<4096, 256, 0, stream>>>(x, p);
    feats_kernel<<<128, 64, 0, stream>>>(p, cw, cb, rot1, crx1, rot2, crx2,
                                         U, crxcs, ev, w0f);
    qstep_a0<<<128,  256, 0, stream>>>(U, crxcs, seed);
    qstep_a1<<<2048, 128, 0, stream>>>(U, crxcs, w0f, seed, sbf);   // FIX: 128 threads
    qstep_b1<<<1024, 256, 0, stream>>>(U, crxcs, sbf, ev);
    head_kernel<<<1, 128, 0, stream>>>(ev, fcw, fcb, (float*)d_out);
}

// Round 6
// 91.870 us; speedup vs baseline: 1.3715x; 1.3715x over previous
//
#include <hip/hip_runtime.h>
#include <hip/hip_bf16.h>

typedef float f2 __attribute__((ext_vector_type(2)));

// ---------------- helpers ----------------

// swizzle for 4096-amp f2 LDS tile: XOR low 4 bits with bits 4-7 (bijective)
#define SWZA(i) ((i) ^ (((i) >> 4) & 15))

// complex 2x2 gate on an amplitude pair; u = {u00r,u00i,u01r,u01i,u10r,u10i,u11r,u11i}
// written as packed-f32 friendly: n = ur*a + ui*swapneg(a) per complex term
__device__ __forceinline__ void gate1q(f2& a0, f2& a1, const float* u) {
    f2 s0 = { -a0.y, a0.x };
    f2 s1 = { -a1.y, a1.x };
    f2 n0 = u[0]*a0 + u[1]*s0 + u[2]*a1 + u[3]*s1;
    f2 n1 = u[4]*a0 + u[5]*s0 + u[6]*a1 + u[7]*s1;
    a0 = n0; a1 = n1;
}

// RX on the (a0,a1) pair: n0 = c*a0 - i*s*a1 ; n1 = -i*s*a0 + c*a1
__device__ __forceinline__ void crx_pair(f2& a0, f2& a1, float c, float s) {
    f2 t0 = { a0.y, -a0.x };
    f2 t1 = { a1.y, -a1.x };
    f2 n0 = c*a0 + s*t1;
    f2 n1 = c*a1 + s*t0;
    a0 = n0; a1 = n1;
}

template<int K, int W>
__device__ __forceinline__ void apply1q_win(f2* a, const float* u) {
    #pragma unroll
    for (int m = 0; m < W / 2; ++m) {
        const int j0 = ((m >> K) << (K + 1)) | (m & ((1 << K) - 1));
        gate1q(a[j0], a[j0 | (1 << K)], u);
    }
}

template<int KC, int KT, int W>
__device__ __forceinline__ void crx_win(f2* a, float c, float s) {
    #pragma unroll
    for (int j = 0; j < W; ++j) {
        if ((j & (1 << KC)) != 0 && (j & (1 << KT)) == 0)
            crx_pair(a[j], a[j | (1 << KT)], c, s);
    }
}

__device__ __forceinline__ void loadU(const float* __restrict__ src, float* u) {
    #pragma unroll
    for (int k = 0; k < 8; ++k) u[k] = src[k];
}

// bf16x2 pack/unpack (RNE)
__device__ __forceinline__ unsigned bf2pack(float x, float y) {
    unsigned ux = __float_as_uint(x); ux = (ux + 0x7FFFu + ((ux >> 16) & 1u)) >> 16;
    unsigned uy = __float_as_uint(y); uy = (uy + 0x7FFFu + ((uy >> 16) & 1u)) >> 16;
    return ux | (uy << 16);
}
__device__ __forceinline__ f2 bf2unpack(unsigned v) {
    f2 r;
    r.x = __uint_as_float(v << 16);
    r.y = __uint_as_float(v & 0xFFFF0000u);
    return r;
}

// ---------------- kernel 1: adaptive pool ----------------
__global__ __launch_bounds__(256) void pool_kernel(const float* __restrict__ x,
                                                   float* __restrict__ p) {
    int blk = blockIdx.x;            // b*32 + j
    int b = blk >> 5, j = blk & 31;
    int c = j >> 4, dd = (j >> 2) & 3, hh = j & 3;
    const float4* xb = (const float4*)(x + (((size_t)(b * 2 + c) * 16 + dd * 4) << 12)
                                         + (size_t)hh * 1024);
    int tid = threadIdx.x;
    float sum = 0.f;
    #pragma unroll
    for (int k = 0; k < 4; ++k) {
        int f = k * 256 + tid;
        int r = f >> 4, col = f & 15;
        int off = (r >> 4) * 1024 + (r & 15) * 16 + col;
        float4 v = xb[off];
        sum += v.x + v.y + v.z + v.w;
    }
    #pragma unroll
    for (int o = 1; o < 64; o <<= 1) sum += __shfl_xor(sum, o);
    __shared__ float red[4];
    if ((tid & 63) == 0) red[tid >> 6] = sum;
    __syncthreads();
    if (tid == 0) p[blk] = (red[0] + red[1] + red[2] + red[3]) * (1.0f / 4096.0f);
}

// ---------------- kernel 2: fused feats + gate precompute + W0 + layer-0 pass A -----
// grid = 128 (one block per batch), 256 threads.
// Phase 1 (few threads): feats GEMV, fused RX*Rot gates for both layers -> Uws (global)
//   + layer-0 gates kept in LDS (uL0/csL0), W0 (layer-0 pass-B as 32x2) -> w0f.
// Phase 2 (all threads): layer-0 pass A (U0..U11 + CRX(0,1)..(10,11)) on e_0 -> seed.
__global__ __launch_bounds__(256) void qstep_a0(const float* __restrict__ p,
                                                const float* __restrict__ cw,
                                                const float* __restrict__ cb,
                                                const float* __restrict__ rot1,
                                                const float* __restrict__ crx1,
                                                const float* __restrict__ rot2,
                                                const float* __restrict__ crx2,
                                                float* __restrict__ Uws,
                                                float* __restrict__ crxcs,
                                                float* __restrict__ ev,
                                                float* __restrict__ w0f,
                                                f2* __restrict__ seed) {
    __shared__ f2 lds[4096];
    __shared__ float pp[32];
    __shared__ float uB[4][8];      // layer-0 U12..U15
    __shared__ float uL0[12][8];    // layer-0 U0..U11
    __shared__ float csL0[24];      // layer-0 CRX(0,1)..(11,12) c/s  (only 0..21 used here)
    int b = blockIdx.x, tid = threadIdx.x;

    if (tid < 32) pp[tid] = p[b * 32 + tid];
    __syncthreads();
    if (tid >= 16 && tid < 32) ev[b * 16 + (tid - 16)] = 0.f;
    if (tid < 16) {
        int q = tid;
        float f = cb[q];
        #pragma unroll
        for (int jj = 0; jj < 32; ++jj) f += pp[jj] * cw[q * 32 + jj];
        float cr = cosf(0.5f * f), sr = sinf(0.5f * f);
        #pragma unroll
        for (int l = 0; l < 2; ++l) {
            const float* rw = (l == 0 ? rot1 : rot2) + q * 3;
            float phi = rw[0], th = rw[1], om = rw[2];
            float ct = cosf(0.5f * th), st = sinf(0.5f * th);
            float aa = 0.5f * (phi + om), dd = 0.5f * (phi - om);
            float ca = cosf(aa), sa = sinf(aa), cd = cosf(dd), sd = sinf(dd);
            float R00r =  ct * ca, R00i = -ct * sa;
            float R01r = -st * cd, R01i = -st * sd;
            float R10r =  st * cd, R10i = -st * sd;
            float R11r =  ct * ca, R11i =  ct * sa;
            float u0 = cr * R00r + sr * R01i;
            float u1 = cr * R00i - sr * R01r;
            float u2 = cr * R01r + sr * R00i;
            float u3 = cr * R01i - sr * R00r;
            float u4 = cr * R10r + sr * R11i;
            float u5 = cr * R10i - sr * R11r;
            float u6 = cr * R11r + sr * R10i;
            float u7 = cr * R11i - sr * R10r;
            float* dst = Uws + ((size_t)(l * 128 + b) * 16 + q) * 8;
            dst[0] = u0; dst[1] = u1; dst[2] = u2; dst[3] = u3;
            dst[4] = u4; dst[5] = u5; dst[6] = u6; dst[7] = u7;
            if (l == 0) {
                float* s = (q < 12) ? uL0[q] : uB[q - 12];
                s[0] = u0; s[1] = u1; s[2] = u2; s[3] = u3;
                s[4] = u4; s[5] = u5; s[6] = u6; s[7] = u7;
            }
            float th2 = (l == 0 ? crx1 : crx2)[q];
            float cc = cosf(0.5f * th2), ss = sinf(0.5f * th2);
            if (l == 0 && q < 12) { csL0[2 * q] = cc; csL0[2 * q + 1] = ss; }
            if (b == 0) {
                crxcs[(l * 16 + q) * 2 + 0] = cc;
                crxcs[(l * 16 + q) * 2 + 1] = ss;
            }
        }
    }
    __syncthreads();

    // W0[b][m][j]: layer-0 pass-B window (U12..U15 + CRX(11,12)..(14,15)) columns j=0,1
    if (tid >= 32 && tid < 34) {
        int j = tid - 32;
        f2 w[32];
        #pragma unroll
        for (int m = 0; m < 32; ++m) w[m] = f2{0.f, 0.f};
        w[j] = f2{1.f, 0.f};
        apply1q_win<1, 32>(w, uB[0]);   // U12
        apply1q_win<2, 32>(w, uB[1]);   // U13
        apply1q_win<3, 32>(w, uB[2]);   // U14
        apply1q_win<4, 32>(w, uB[3]);   // U15
        crx_win<0, 1, 32>(w, cosf(0.5f * crx1[11]), sinf(0.5f * crx1[11]));  // CRX(11,12)
        crx_win<1, 2, 32>(w, cosf(0.5f * crx1[12]), sinf(0.5f * crx1[12]));  // CRX(12,13)
        crx_win<2, 3, 32>(w, cosf(0.5f * crx1[13]), sinf(0.5f * crx1[13]));  // CRX(13,14)
        crx_win<3, 4, 32>(w, cosf(0.5f * crx1[14]), sinf(0.5f * crx1[14]));  // CRX(14,15)
        #pragma unroll
        for (int m = 0; m < 32; ++m) {
            float* d = w0f + ((size_t)(b * 32 + m) * 2 + j) * 2;
            d[0] = w[m].x; d[1] = w[m].y;
        }
    }

    // ---- layer-0 pass A on e_0 (4096-amp support, bits 0-11) ----
    #pragma unroll
    for (int j = 0; j < 16; ++j) lds[SWZA(j * 256 + tid)] = f2{0.f, 0.f};
    if (tid == 0) lds[SWZA(0)] = f2{1.f, 0.f};
    __syncthreads();

    f2 a[16];

    // SR1: bits 0..3
    {
        #pragma unroll
        for (int j = 0; j < 16; ++j) a[j] = lds[SWZA((tid << 4) | j)];
        apply1q_win<0, 16>(a, uL0[0]);
        apply1q_win<1, 16>(a, uL0[1]);
        apply1q_win<2, 16>(a, uL0[2]);
        apply1q_win<3, 16>(a, uL0[3]);
        crx_win<0, 1, 16>(a, csL0[0], csL0[1]);
        crx_win<1, 2, 16>(a, csL0[2], csL0[3]);
        crx_win<2, 3, 16>(a, csL0[4], csL0[5]);
        #pragma unroll
        for (int j = 0; j < 16; ++j) lds[SWZA((tid << 4) | j)] = a[j];
    }
    __syncthreads();

    // SR2: bits 3..6
    {
        int lo = tid & 7, hi = (tid >> 3) << 7;
        #pragma unroll
        for (int j = 0; j < 16; ++j) a[j] = lds[SWZA(lo | (j << 3) | hi)];
        apply1q_win<1, 16>(a, uL0[4]);
        apply1q_win<2, 16>(a, uL0[5]);
        apply1q_win<3, 16>(a, uL0[6]);
        crx_win<0, 1, 16>(a, csL0[6],  csL0[7]);
        crx_win<1, 2, 16>(a, csL0[8],  csL0[9]);
        crx_win<2, 3, 16>(a, csL0[10], csL0[11]);
        #pragma unroll
        for (int j = 0; j < 16; ++j) lds[SWZA(lo | (j << 3) | hi)] = a[j];
    }
    __syncthreads();

    // SR3: bits 6..9
    {
        int lo = tid & 63, hi = (tid >> 6) << 10;
        #pragma unroll
        for (int j = 0; j < 16; ++j) a[j] = lds[SWZA(lo | (j << 6) | hi)];
        apply1q_win<1, 16>(a, uL0[7]);
        apply1q_win<2, 16>(a, uL0[8]);
        apply1q_win<3, 16>(a, uL0[9]);
        crx_win<0, 1, 16>(a, csL0[12], csL0[13]);
        crx_win<1, 2, 16>(a, csL0[14], csL0[15]);
        crx_win<2, 3, 16>(a, csL0[16], csL0[17]);
        #pragma unroll
        for (int j = 0; j < 16; ++j) lds[SWZA(lo | (j << 6) | hi)] = a[j];
    }
    __syncthreads();

    // SR4: bits 8..11 ; store directly from regs (idx = tid | (j<<8))
    {
        #pragma unroll
        for (int j = 0; j < 16; ++j) a[j] = lds[SWZA(tid | (j << 8))];
        apply1q_win<2, 16>(a, uL0[10]);
        apply1q_win<3, 16>(a, uL0[11]);
        crx_win<1, 2, 16>(a, csL0[18], csL0[19]);
        crx_win<2, 3, 16>(a, csL0[20], csL0[21]);
        #pragma unroll
        for (int j = 0; j < 16; ++j) seed[((size_t)b << 12) + (j << 8) + tid] = a[j];
    }
}

// ---------------- kernel 3: layer-1 pass A with fused layer-0 B expansion ------------
// grid = 2048 (b = blk>>4, chunk = blk&15) ; 256 threads ; LDS 32 KB (f2)
// Loads the 4096-amp seed (L2-hot), applies W0 (+ runtime layer-0 CRX(15,0)),
// then layer-1 U0..U11 + CRX(0,1)..(10,11); writes bf16 state chunk.
__global__ __launch_bounds__(256) void qstep_a1(const float* __restrict__ Uws,
                                                const float* __restrict__ crxcs,
                                                const float* __restrict__ w0f,
                                                const f2* __restrict__ seed,
                                                unsigned* __restrict__ sbf) {
    __shared__ f2 lds[4096];
    int tid = threadIdx.x;
    int b = blockIdx.x >> 4, chunk = blockIdx.x & 15;

    // ---- fused layer-0 B: a[jj] for idx=(tid<<4)|jj (t = idx bits 0-10, bit11 = tid>>7)
    int t0 = (tid & 127) << 4;
    const float4* p0 = (const float4*)(seed + ((size_t)b << 12) + t0);
    const float4* p1 = (const float4*)(seed + ((size_t)b << 12) + 2048 + t0);
    f2 r0[16], r1[16];
    #pragma unroll
    for (int k = 0; k < 8; ++k) {
        float4 v = p0[k]; r0[2 * k] = f2{v.x, v.y}; r0[2 * k + 1] = f2{v.z, v.w};
        float4 w = p1[k]; r1[2 * k] = f2{w.x, w.y}; r1[2 * k + 1] = f2{w.z, w.w};
    }
    int m = (chunk << 1) | (tid >> 7);
    const float* wr = w0f + (size_t)(b * 32 + m) * 4;
    float w0r = wr[0], w0i = wr[1], w1r = wr[2], w1i = wr[3];
    f2 a[16];
    if (chunk >= 8) {   // m bit4 = 1 -> layer-0 CRX(15,0) active on these m
        float c = crxcs[30], s = crxcs[31];
        #pragma unroll
        for (int e = 0; e < 16; e += 2) {
            int o = e + 1;
            // RX(theta15) on qubit-0 pair (even,odd), then W0 combine
            f2 te = { r0[o].y, -r0[o].x };
            f2 to = { r0[e].y, -r0[e].x };
            f2 v0e = c * r0[e] + s * te;
            f2 v0o = c * r0[o] + s * to;
            f2 ue = { r1[o].y, -r1[o].x };
            f2 uo = { r1[e].y, -r1[e].x };
            f2 v1e = c * r1[e] + s * ue;
            f2 v1o = c * r1[o] + s * uo;
            f2 s0e = { -v0e.y, v0e.x }, s1e = { -v1e.y, v1e.x };
            f2 s0o = { -v0o.y, v0o.x }, s1o = { -v1o.y, v1o.x };
            a[e] = w0r * v0e + w0i * s0e + w1r * v1e + w1i * s1e;
            a[o] = w0r * v0o + w0i * s0o + w1r * v1o + w1i * s1o;
        }
    } else {
        #pragma unroll
        for (int e = 0; e < 16; ++e) {
            f2 s0 = { -r0[e].y, r0[e].x };
            f2 s1 = { -r1[e].y, r1[e].x };
            a[e] = w0r * r0[e] + w0i * s0 + w1r * r1[e] + w1i * s1;
        }
    }

    const float* Ub = Uws + (size_t)(128 + b) * 128;   // layer 1
    const float* cs = crxcs + 32;                      // layer 1
    float u[8];

    // SR1: bits 0..3 (regs already in this layout)
    {
        loadU(Ub + 0 * 8, u);  apply1q_win<0, 16>(a, u);
        loadU(Ub + 1 * 8, u);  apply1q_win<1, 16>(a, u);
        loadU(Ub + 2 * 8, u);  apply1q_win<2, 16>(a, u);
        loadU(Ub + 3 * 8, u);  apply1q_win<3, 16>(a, u);
        crx_win<0, 1, 16>(a, cs[0], cs[1]);
        crx_win<1, 2, 16>(a, cs[2], cs[3]);
        crx_win<2, 3, 16>(a, cs[4], cs[5]);
        #pragma unroll
        for (int j = 0; j < 16; ++j) lds[SWZA((tid << 4) | j)] = a[j];
    }
    __syncthreads();

    // SR2: bits 3..6
    {
        int lo = tid & 7, hi = (tid >> 3) << 7;
        #pragma unroll
        for (int j = 0; j < 16; ++j) a[j] = lds[SWZA(lo | (j << 3) | hi)];
        loadU(Ub + 4 * 8, u);  apply1q_win<1, 16>(a, u);
        loadU(Ub + 5 * 8, u);  apply1q_win<2, 16>(a, u);
        loadU(Ub + 6 * 8, u);  apply1q_win<3, 16>(a, u);
        crx_win<0, 1, 16>(a, cs[6],  cs[7]);
        crx_win<1, 2, 16>(a, cs[8],  cs[9]);
        crx_win<2, 3, 16>(a, cs[10], cs[11]);
        #pragma unroll
        for (int j = 0; j < 16; ++j) lds[SWZA(lo | (j << 3) | hi)] = a[j];
    }
    __syncthreads();

    // SR3: bits 6..9
    {
        int lo = tid & 63, hi = (tid >> 6) << 10;
        #pragma unroll
        for (int j = 0; j < 16; ++j) a[j] = lds[SWZA(lo | (j << 6) | hi)];
        loadU(Ub + 7 * 8, u);  apply1q_win<1, 16>(a, u);
        loadU(Ub + 8 * 8, u);  apply1q_win<2, 16>(a, u);
        loadU(Ub + 9 * 8, u);  apply1q_win<3, 16>(a, u);
        crx_win<0, 1, 16>(a, cs[12], cs[13]);
        crx_win<1, 2, 16>(a, cs[14], cs[15]);
        crx_win<2, 3, 16>(a, cs[16], cs[17]);
        #pragma unroll
        for (int j = 0; j < 16; ++j) lds[SWZA(lo | (j << 6) | hi)] = a[j];
    }
    __syncthreads();

    // SR4: bits 8..11 ; store bf16 directly from regs (idx = tid | (j<<8))
    {
        #pragma unroll
        for (int j = 0; j < 16; ++j) a[j] = lds[SWZA(tid | (j << 8))];
        loadU(Ub + 10 * 8, u);  apply1q_win<2, 16>(a, u);
        loadU(Ub + 11 * 8, u);  apply1q_win<3, 16>(a, u);
        crx_win<1, 2, 16>(a, cs[18], cs[19]);
        crx_win<2, 3, 16>(a, cs[20], cs[21]);
        size_t base = ((size_t)b << 16) + ((size_t)chunk << 12);
        #pragma unroll
        for (int j = 0; j < 16; ++j)
            sbf[base + (j << 8) + tid] = bf2pack(a[j].x, a[j].y);
    }
}

// ---------------- kernel 4: layer-1 pass B + EV reduce (bf16 state in) ---------------
// grid: 1024 (b = blk>>3, part = blk&7) ; 256 threads ; t = idx bits 0..10
__global__ __launch_bounds__(256) void qstep_b1(const float* __restrict__ Uws,
                                                const float* __restrict__ crxcs,
                                                const unsigned* __restrict__ sbf,
                                                float* __restrict__ ev) {
    int tid = threadIdx.x;
    int b = blockIdx.x >> 3, part = blockIdx.x & 7;
    int t = part * 256 + tid;
    size_t base = ((size_t)b << 16) + t;
    f2 a[32];
    #pragma unroll
    for (int j = 0; j < 32; ++j) a[j] = bf2unpack(sbf[base + ((size_t)j << 11)]);

    const float* Ub = Uws + (size_t)(128 + b) * 128;
    const float* cs = crxcs + 32;
    float u[8];
    loadU(Ub + 12 * 8, u);  apply1q_win<1, 32>(a, u);
    loadU(Ub + 13 * 8, u);  apply1q_win<2, 32>(a, u);
    loadU(Ub + 14 * 8, u);  apply1q_win<3, 32>(a, u);
    loadU(Ub + 15 * 8, u);  apply1q_win<4, 32>(a, u);
    crx_win<0, 1, 32>(a, cs[22], cs[23]);
    crx_win<1, 2, 32>(a, cs[24], cs[25]);
    crx_win<2, 3, 32>(a, cs[26], cs[27]);
    crx_win<3, 4, 32>(a, cs[28], cs[29]);
    {   // CRX(15,0): control = j bit 4, target = idx bit 0 = lane bit 0
        float c = cs[30], s = cs[31];
        #pragma unroll
        for (int j = 16; j < 32; ++j) {
            float pr = __shfl_xor(a[j].x, 1);
            float pi = __shfl_xor(a[j].y, 1);
            float nr = c * a[j].x + s * pi;
            float ni = c * a[j].y - s * pr;
            a[j].x = nr; a[j].y = ni;
        }
    }

    float P = 0.f, S0 = 0.f, S1 = 0.f, S2 = 0.f, S3 = 0.f, S4 = 0.f;
    #pragma unroll
    for (int j = 0; j < 32; ++j) {
        float pr = a[j].x * a[j].x + a[j].y * a[j].y;
        P += pr;
        S0 += (j & 1)  ? -pr : pr;
        S1 += (j & 2)  ? -pr : pr;
        S2 += (j & 4)  ? -pr : pr;
        S3 += (j & 8)  ? -pr : pr;
        S4 += (j & 16) ? -pr : pr;
    }
    float evq[16];
    #pragma unroll
    for (int q = 0; q < 11; ++q) evq[q] = ((t >> q) & 1) ? -P : P;
    evq[11] = S0; evq[12] = S1; evq[13] = S2; evq[14] = S3; evq[15] = S4;
    #pragma unroll
    for (int q = 0; q < 16; ++q) {
        float v = evq[q];
        #pragma unroll
        for (int o = 32; o >= 1; o >>= 1) v += __shfl_xor(v, o);
        evq[q] = v;
    }
    __shared__ float red[4][16];
    int wave = tid >> 6, lane = tid & 63;
    if (lane == 0) {
        #pragma unroll
        for (int q = 0; q < 16; ++q) red[wave][q] = evq[q];
    }
    __syncthreads();
    if (tid < 16) {
        float v = red[0][tid] + red[1][tid] + red[2][tid] + red[3][tid];
        atomicAdd(&ev[b * 16 + tid], v);
    }
}

// ---------------- kernel 5: head + log_softmax ----------------
__global__ __launch_bounds__(128) void head_kernel(const float* __restrict__ ev,
                                                   const float* __restrict__ fcw,
                                                   const float* __restrict__ fcb,
                                                   float* __restrict__ out) {
    int b = threadIdx.x;
    if (b >= 128) return;
    float e[16];
    #pragma unroll
    for (int q = 0; q < 16; ++q) e[q] = ev[b * 16 + q];
    float lg[16];
    float mx = -1e30f;
    #pragma unroll
    for (int c = 0; c < 16; ++c) {
        float v = fcb[c];
        #pragma unroll
        for (int q = 0; q < 16; ++q) v += e[q] * fcw[c * 16 + q];
        lg[c] = v;
        mx = fmaxf(mx, v);
    }
    float se = 0.f;
    #pragma unroll
    for (int c = 0; c < 16; ++c) se += expf(lg[c] - mx);
    float lse = mx + logf(se);
    #pragma unroll
    for (int c = 0; c < 16; ++c) out[b * 16 + c] = lg[c] - lse;
}

// ---------------- launch ----------------
extern "C" void kernel_launch(void* const* d_in, const int* in_sizes, int n_in,
                              void* d_out, int out_size, void* d_ws, size_t ws_size,
                              hipStream_t stream) {
    const float* x    = (const float*)d_in[0];
    const float* cw   = (const float*)d_in[1];
    const float* cb   = (const float*)d_in[2];
    const float* rot1 = (const float*)d_in[3];
    const float* crx1 = (const float*)d_in[4];
    const float* rot2 = (const float*)d_in[5];
    const float* crx2 = (const float*)d_in[6];
    const float* fcw  = (const float*)d_in[7];
    const float* fcb  = (const float*)d_in[8];

    float* ws    = (float*)d_ws;
    float* p     = ws;                         // 4096
    float* U     = ws + 4096;                  // 32768 -> ends 36864
    float* crxcs = ws + 36864;                 // 64
    float* ev    = ws + 36928;                 // 2048 -> ends 38976
    float* w0f   = ws + 40960;                 // 16384 -> ends 57344
    f2* seed     = (f2*)(ws + 65536);          // 128*4096 f2 = 4 MiB
    unsigned* sbf = (unsigned*)(ws + 1114112); // 128*65536 uint = 32 MiB

    pool_kernel<<<4096, 256, 0, stream>>>(x, p);
    qstep_a0<<<128,  256, 0, stream>>>(p, cw, cb, rot1, crx1, rot2, crx2,
                                       U, crxcs, ev, w0f, seed);
    qstep_a1<<<2048, 256, 0, stream>>>(U, crxcs, w0f, seed, sbf);
    qstep_b1<<<1024, 256, 0, stream>>>(U, crxcs, sbf, ev);
    head_kernel<<<1, 128, 0, stream>>>(ev, fcw, fcb, (float*)d_out);
}

// Round 7
// 86.864 us; speedup vs baseline: 1.4505x; 1.0576x over previous
//
#include <hip/hip_runtime.h>
#include <hip/hip_bf16.h>

typedef float f2 __attribute__((ext_vector_type(2)));

// ---------------- helpers ----------------

// swizzle for 4096-amp f2 LDS tile: XOR low 4 bits with bits 4-7 (bijective)
#define SWZA(i) ((i) ^ (((i) >> 4) & 15))

// complex 2x2 gate on an amplitude pair; u = {u00r,u00i,u01r,u01i,u10r,u10i,u11r,u11i}
__device__ __forceinline__ void gate1q(f2& a0, f2& a1, const float* u) {
    f2 s0 = { -a0.y, a0.x };
    f2 s1 = { -a1.y, a1.x };
    f2 n0 = u[0]*a0 + u[1]*s0 + u[2]*a1 + u[3]*s1;
    f2 n1 = u[4]*a0 + u[5]*s0 + u[6]*a1 + u[7]*s1;
    a0 = n0; a1 = n1;
}

// plain 1q gate over W-amp window, target bit K
template<int K, int W>
__device__ __forceinline__ void apply1q_win(f2* a, const float* u) {
    #pragma unroll
    for (int m = 0; m < W / 2; ++m) {
        const int j0 = ((m >> K) << (K + 1)) | (m & ((1 << K) - 1));
        gate1q(a[j0], a[j0 | (1 << K)], u);
    }
}

// merged (U_q then CRX(q-1,q)) : control-selected 2x2. u16 = {U | RX*U}
// target bit K, control bit KC (both window-local, compile-time select)
template<int K, int KC, int W>
__device__ __forceinline__ void apply1q_mg(f2* a, const float* u16) {
    #pragma unroll
    for (int m = 0; m < W / 2; ++m) {
        const int j0 = ((m >> K) << (K + 1)) | (m & ((1 << K) - 1));
        const float* uu = u16 + (((j0 >> KC) & 1) << 3);
        gate1q(a[j0], a[j0 | (1 << K)], uu);
    }
}

__device__ __forceinline__ void loadU16(const float* __restrict__ src, float* u) {
    #pragma unroll
    for (int k = 0; k < 16; ++k) u[k] = src[k];
}

// bf16x2 pack/unpack (RNE)
__device__ __forceinline__ unsigned bf2pack(float x, float y) {
    unsigned ux = __float_as_uint(x); ux = (ux + 0x7FFFu + ((ux >> 16) & 1u)) >> 16;
    unsigned uy = __float_as_uint(y); uy = (uy + 0x7FFFu + ((uy >> 16) & 1u)) >> 16;
    return ux | (uy << 16);
}
__device__ __forceinline__ f2 bf2unpack(unsigned v) {
    f2 r;
    r.x = __uint_as_float(v << 16);
    r.y = __uint_as_float(v & 0xFFFF0000u);
    return r;
}

// ---------------- kernel 1: adaptive pool ----------------
__global__ __launch_bounds__(256) void pool_kernel(const float* __restrict__ x,
                                                   float* __restrict__ p) {
    int blk = blockIdx.x;            // b*32 + j
    int b = blk >> 5, j = blk & 31;
    int c = j >> 4, dd = (j >> 2) & 3, hh = j & 3;
    const float4* xb = (const float4*)(x + (((size_t)(b * 2 + c) * 16 + dd * 4) << 12)
                                         + (size_t)hh * 1024);
    int tid = threadIdx.x;
    float sum = 0.f;
    #pragma unroll
    for (int k = 0; k < 4; ++k) {
        int f = k * 256 + tid;
        int r = f >> 4, col = f & 15;
        int off = (r >> 4) * 1024 + (r & 15) * 16 + col;
        float4 v = xb[off];
        sum += v.x + v.y + v.z + v.w;
    }
    #pragma unroll
    for (int o = 1; o < 64; o <<= 1) sum += __shfl_xor(sum, o);
    __shared__ float red[4];
    if ((tid & 63) == 0) red[tid >> 6] = sum;
    __syncthreads();
    if (tid == 0) p[blk] = (red[0] + red[1] + red[2] + red[3]) * (1.0f / 4096.0f);
}

// ---------------- kernel 2: fused feats + merged-gate precompute + W0 + layer-0 A ---
// Uws[l][b][q][16] = {U_q (8) | RX(crx[q-1])*U_q (8)}  (q=0: both halves = U_0)
__global__ __launch_bounds__(256) void qstep_a0(const float* __restrict__ p,
                                                const float* __restrict__ cw,
                                                const float* __restrict__ cb,
                                                const float* __restrict__ rot1,
                                                const float* __restrict__ crx1,
                                                const float* __restrict__ rot2,
                                                const float* __restrict__ crx2,
                                                float* __restrict__ Uws,
                                                float* __restrict__ crxcs,
                                                float* __restrict__ ev,
                                                float* __restrict__ w0f,
                                                f2* __restrict__ seed) {
    __shared__ f2 lds[4096];
    __shared__ float pp[32];
    __shared__ float uB[4][16];     // layer-0 merged U12..U15
    __shared__ float uL0[12][16];   // layer-0 merged U0..U11
    int b = blockIdx.x, tid = threadIdx.x;

    if (tid < 32) pp[tid] = p[b * 32 + tid];
    __syncthreads();
    if (tid >= 16 && tid < 32) ev[b * 16 + (tid - 16)] = 0.f;
    if (tid < 16) {
        int q = tid;
        float f = cb[q];
        #pragma unroll
        for (int jj = 0; jj < 32; ++jj) f += pp[jj] * cw[q * 32 + jj];
        float cr = cosf(0.5f * f), sr = sinf(0.5f * f);
        #pragma unroll
        for (int l = 0; l < 2; ++l) {
            const float* rw = (l == 0 ? rot1 : rot2) + q * 3;
            float phi = rw[0], th = rw[1], om = rw[2];
            float ct = cosf(0.5f * th), st = sinf(0.5f * th);
            float aa = 0.5f * (phi + om), dd = 0.5f * (phi - om);
            float ca = cosf(aa), sa = sinf(aa), cd = cosf(dd), sd = sinf(dd);
            float R00r =  ct * ca, R00i = -ct * sa;
            float R01r = -st * cd, R01i = -st * sd;
            float R10r =  st * cd, R10i = -st * sd;
            float R11r =  ct * ca, R11i =  ct * sa;
            float u0 = cr * R00r + sr * R01i;
            float u1 = cr * R00i - sr * R01r;
            float u2 = cr * R01r + sr * R00i;
            float u3 = cr * R01i - sr * R00r;
            float u4 = cr * R10r + sr * R11i;
            float u5 = cr * R10i - sr * R11r;
            float u6 = cr * R11r + sr * R10i;
            float u7 = cr * R11i - sr * R10r;
            // merged second half: M1 = RX(crx[q-1]) * U
            float g[16];
            g[0] = u0; g[1] = u1; g[2] = u2; g[3] = u3;
            g[4] = u4; g[5] = u5; g[6] = u6; g[7] = u7;
            if (q >= 1) {
                float thc = (l == 0 ? crx1 : crx2)[q - 1];
                float c2 = cosf(0.5f * thc), s2 = sinf(0.5f * thc);
                g[8]  = c2*u0 + s2*u5;  g[9]  = c2*u1 - s2*u4;
                g[10] = c2*u2 + s2*u7;  g[11] = c2*u3 - s2*u6;
                g[12] = c2*u4 + s2*u1;  g[13] = c2*u5 - s2*u0;
                g[14] = c2*u6 + s2*u3;  g[15] = c2*u7 - s2*u2;
            } else {
                #pragma unroll
                for (int k = 0; k < 8; ++k) g[8 + k] = g[k];
            }
            float* dst = Uws + ((size_t)(l * 128 + b) * 16 + q) * 16;
            #pragma unroll
            for (int k = 0; k < 16; ++k) dst[k] = g[k];
            if (l == 0) {
                float* s = (q < 12) ? uL0[q] : uB[q - 12];
                #pragma unroll
                for (int k = 0; k < 16; ++k) s[k] = g[k];
            }
            float th2 = (l == 0 ? crx1 : crx2)[q];
            float cc = cosf(0.5f * th2), ss = sinf(0.5f * th2);
            if (b == 0) {
                crxcs[(l * 16 + q) * 2 + 0] = cc;
                crxcs[(l * 16 + q) * 2 + 1] = ss;
            }
        }
    }
    __syncthreads();

    // W0[b][m][j]: layer-0 pass-B window (merged U12..U15 incl CRX(11,12)..(14,15))
    // applied to e_j, input bits 12..15 = 0.  window bit k = qubit 11+k.
    if (tid >= 32 && tid < 34) {
        int j = tid - 32;
        f2 w[32];
        #pragma unroll
        for (int m = 0; m < 32; ++m) w[m] = f2{0.f, 0.f};
        w[j] = f2{1.f, 0.f};
        apply1q_mg<1, 0, 32>(w, uB[0]);   // U12 + CRX(11,12)
        apply1q_mg<2, 1, 32>(w, uB[1]);   // U13 + CRX(12,13)
        apply1q_mg<3, 2, 32>(w, uB[2]);   // U14 + CRX(13,14)
        apply1q_mg<4, 3, 32>(w, uB[3]);   // U15 + CRX(14,15)
        #pragma unroll
        for (int m = 0; m < 32; ++m) {
            float* d = w0f + ((size_t)(b * 32 + m) * 2 + j) * 2;
            d[0] = w[m].x; d[1] = w[m].y;
        }
    }

    // ---- layer-0 pass A on e_0 (bits 0-11): merged gates U0..U11 ----
    #pragma unroll
    for (int j = 0; j < 16; ++j) lds[SWZA(j * 256 + tid)] = f2{0.f, 0.f};
    if (tid == 0) lds[SWZA(0)] = f2{1.f, 0.f};
    __syncthreads();

    f2 a[16];

    // SR1: bits 0..3
    {
        #pragma unroll
        for (int j = 0; j < 16; ++j) a[j] = lds[SWZA((tid << 4) | j)];
        apply1q_win<0, 16>(a, uL0[0]);       // U0
        apply1q_mg<1, 0, 16>(a, uL0[1]);     // U1 + CRX(0,1)
        apply1q_mg<2, 1, 16>(a, uL0[2]);     // U2 + CRX(1,2)
        apply1q_mg<3, 2, 16>(a, uL0[3]);     // U3 + CRX(2,3)
        #pragma unroll
        for (int j = 0; j < 16; ++j) lds[SWZA((tid << 4) | j)] = a[j];
    }
    __syncthreads();

    // SR2: bits 3..6
    {
        int lo = tid & 7, hi = (tid >> 3) << 7;
        #pragma unroll
        for (int j = 0; j < 16; ++j) a[j] = lds[SWZA(lo | (j << 3) | hi)];
        apply1q_mg<1, 0, 16>(a, uL0[4]);     // U4 + CRX(3,4)
        apply1q_mg<2, 1, 16>(a, uL0[5]);     // U5 + CRX(4,5)
        apply1q_mg<3, 2, 16>(a, uL0[6]);     // U6 + CRX(5,6)
        #pragma unroll
        for (int j = 0; j < 16; ++j) lds[SWZA(lo | (j << 3) | hi)] = a[j];
    }
    __syncthreads();

    // SR3: bits 6..9
    {
        int lo = tid & 63, hi = (tid >> 6) << 10;
        #pragma unroll
        for (int j = 0; j < 16; ++j) a[j] = lds[SWZA(lo | (j << 6) | hi)];
        apply1q_mg<1, 0, 16>(a, uL0[7]);     // U7 + CRX(6,7)
        apply1q_mg<2, 1, 16>(a, uL0[8]);     // U8 + CRX(7,8)
        apply1q_mg<3, 2, 16>(a, uL0[9]);     // U9 + CRX(8,9)
        #pragma unroll
        for (int j = 0; j < 16; ++j) lds[SWZA(lo | (j << 6) | hi)] = a[j];
    }
    __syncthreads();

    // SR4: bits 8..11 ; store directly from regs (idx = tid | (j<<8))
    {
        #pragma unroll
        for (int j = 0; j < 16; ++j) a[j] = lds[SWZA(tid | (j << 8))];
        apply1q_mg<2, 1, 16>(a, uL0[10]);    // U10 + CRX(9,10)
        apply1q_mg<3, 2, 16>(a, uL0[11]);    // U11 + CRX(10,11)
        #pragma unroll
        for (int j = 0; j < 16; ++j) seed[((size_t)b << 12) + (j << 8) + tid] = a[j];
    }
}

// ---------------- kernel 3: layer-1 pass A with fused layer-0 B expansion ------------
// grid = 2048 (b = blk>>4, chunk = blk&15) ; 256 threads ; LDS 32 KB (f2)
__global__ __launch_bounds__(256) void qstep_a1(const float* __restrict__ Uws,
                                                const float* __restrict__ crxcs,
                                                const float* __restrict__ w0f,
                                                const f2* __restrict__ seed,
                                                unsigned* __restrict__ sbf) {
    __shared__ f2 lds[4096];
    int tid = threadIdx.x;
    int b = blockIdx.x >> 4, chunk = blockIdx.x & 15;

    // ---- fused layer-0 B: a[jj] for idx=(tid<<4)|jj (t = idx bits 0-10, bit11 = tid>>7)
    int t0 = (tid & 127) << 4;
    const float4* p0 = (const float4*)(seed + ((size_t)b << 12) + t0);
    const float4* p1 = (const float4*)(seed + ((size_t)b << 12) + 2048 + t0);
    f2 r0[16], r1[16];
    #pragma unroll
    for (int k = 0; k < 8; ++k) {
        float4 v = p0[k]; r0[2 * k] = f2{v.x, v.y}; r0[2 * k + 1] = f2{v.z, v.w};
        float4 w = p1[k]; r1[2 * k] = f2{w.x, w.y}; r1[2 * k + 1] = f2{w.z, w.w};
    }
    int m = (chunk << 1) | (tid >> 7);
    const float* wr = w0f + (size_t)(b * 32 + m) * 4;
    float w0r = wr[0], w0i = wr[1], w1r = wr[2], w1i = wr[3];
    f2 a[16];
    if (chunk >= 8) {   // m bit4 = 1 -> layer-0 CRX(15,0) active on these m
        float c = crxcs[30], s = crxcs[31];
        #pragma unroll
        for (int e = 0; e < 16; e += 2) {
            int o = e + 1;
            f2 te = { r0[o].y, -r0[o].x };
            f2 to = { r0[e].y, -r0[e].x };
            f2 v0e = c * r0[e] + s * te;
            f2 v0o = c * r0[o] + s * to;
            f2 ue = { r1[o].y, -r1[o].x };
            f2 uo = { r1[e].y, -r1[e].x };
            f2 v1e = c * r1[e] + s * ue;
            f2 v1o = c * r1[o] + s * uo;
            f2 s0e = { -v0e.y, v0e.x }, s1e = { -v1e.y, v1e.x };
            f2 s0o = { -v0o.y, v0o.x }, s1o = { -v1o.y, v1o.x };
            a[e] = w0r * v0e + w0i * s0e + w1r * v1e + w1i * s1e;
            a[o] = w0r * v0o + w0i * s0o + w1r * v1o + w1i * s1o;
        }
    } else {
        #pragma unroll
        for (int e = 0; e < 16; ++e) {
            f2 s0 = { -r0[e].y, r0[e].x };
            f2 s1 = { -r1[e].y, r1[e].x };
            a[e] = w0r * r0[e] + w0i * s0 + w1r * r1[e] + w1i * s1;
        }
    }

    const float* Ub = Uws + (size_t)(128 + b) * 256;   // layer 1, merged gates (16 ea)
    float u[16];

    // SR1: bits 0..3 (regs already in this layout)
    {
        loadU16(Ub + 0 * 16, u);  apply1q_win<0, 16>(a, u);     // U0
        loadU16(Ub + 1 * 16, u);  apply1q_mg<1, 0, 16>(a, u);   // U1 + CRX(0,1)
        loadU16(Ub + 2 * 16, u);  apply1q_mg<2, 1, 16>(a, u);   // U2 + CRX(1,2)
        loadU16(Ub + 3 * 16, u);  apply1q_mg<3, 2, 16>(a, u);   // U3 + CRX(2,3)
        #pragma unroll
        for (int j = 0; j < 16; ++j) lds[SWZA((tid << 4) | j)] = a[j];
    }
    __syncthreads();

    // SR2: bits 3..6
    {
        int lo = tid & 7, hi = (tid >> 3) << 7;
        #pragma unroll
        for (int j = 0; j < 16; ++j) a[j] = lds[SWZA(lo | (j << 3) | hi)];
        loadU16(Ub + 4 * 16, u);  apply1q_mg<1, 0, 16>(a, u);   // U4 + CRX(3,4)
        loadU16(Ub + 5 * 16, u);  apply1q_mg<2, 1, 16>(a, u);   // U5 + CRX(4,5)
        loadU16(Ub + 6 * 16, u);  apply1q_mg<3, 2, 16>(a, u);   // U6 + CRX(5,6)
        #pragma unroll
        for (int j = 0; j < 16; ++j) lds[SWZA(lo | (j << 3) | hi)] = a[j];
    }
    __syncthreads();

    // SR3: bits 6..9
    {
        int lo = tid & 63, hi = (tid >> 6) << 10;
        #pragma unroll
        for (int j = 0; j < 16; ++j) a[j] = lds[SWZA(lo | (j << 6) | hi)];
        loadU16(Ub + 7 * 16, u);  apply1q_mg<1, 0, 16>(a, u);   // U7 + CRX(6,7)
        loadU16(Ub + 8 * 16, u);  apply1q_mg<2, 1, 16>(a, u);   // U8 + CRX(7,8)
        loadU16(Ub + 9 * 16, u);  apply1q_mg<3, 2, 16>(a, u);   // U9 + CRX(8,9)
        #pragma unroll
        for (int j = 0; j < 16; ++j) lds[SWZA(lo | (j << 6) | hi)] = a[j];
    }
    __syncthreads();

    // SR4: bits 8..11 ; store bf16 directly from regs (idx = tid | (j<<8))
    {
        #pragma unroll
        for (int j = 0; j < 16; ++j) a[j] = lds[SWZA(tid | (j << 8))];
        loadU16(Ub + 10 * 16, u);  apply1q_mg<2, 1, 16>(a, u);  // U10 + CRX(9,10)
        loadU16(Ub + 11 * 16, u);  apply1q_mg<3, 2, 16>(a, u);  // U11 + CRX(10,11)
        size_t base = ((size_t)b << 16) + ((size_t)chunk << 12);
        #pragma unroll
        for (int j = 0; j < 16; ++j)
            sbf[base + (j << 8) + tid] = bf2pack(a[j].x, a[j].y);
    }
}

// ---------------- kernel 4: layer-1 pass B + EV reduce (bf16 state in) ---------------
// grid: 1024 (b = blk>>3, part = blk&7) ; 256 threads ; t = idx bits 0..10
__global__ __launch_bounds__(256) void qstep_b1(const float* __restrict__ Uws,
                                                const float* __restrict__ crxcs,
                                                const unsigned* __restrict__ sbf,
                                                float* __restrict__ ev) {
    int tid = threadIdx.x;
    int b = blockIdx.x >> 3, part = blockIdx.x & 7;
    int t = part * 256 + tid;
    size_t base = ((size_t)b << 16) + t;
    f2 a[32];
    #pragma unroll
    for (int j = 0; j < 32; ++j) a[j] = bf2unpack(sbf[base + ((size_t)j << 11)]);

    const float* Ub = Uws + (size_t)(128 + b) * 256;
    const float* cs = crxcs + 32;
    float u[16];
    loadU16(Ub + 12 * 16, u);  apply1q_mg<1, 0, 32>(a, u);  // U12 + CRX(11,12)
    loadU16(Ub + 13 * 16, u);  apply1q_mg<2, 1, 32>(a, u);  // U13 + CRX(12,13)
    loadU16(Ub + 14 * 16, u);  apply1q_mg<3, 2, 32>(a, u);  // U14 + CRX(13,14)
    loadU16(Ub + 15 * 16, u);  apply1q_mg<4, 3, 32>(a, u);  // U15 + CRX(14,15)
    {   // CRX(15,0): control = j bit 4, target = idx bit 0 = lane bit 0
        float c = cs[30], s = cs[31];
        #pragma unroll
        for (int j = 16; j < 32; ++j) {
            float pr = __shfl_xor(a[j].x, 1);
            float pi = __shfl_xor(a[j].y, 1);
            float nr = c * a[j].x + s * pi;
            float ni = c * a[j].y - s * pr;
            a[j].x = nr; a[j].y = ni;
        }
    }

    float P = 0.f, S0 = 0.f, S1 = 0.f, S2 = 0.f, S3 = 0.f, S4 = 0.f;
    #pragma unroll
    for (int j = 0; j < 32; ++j) {
        float pr = a[j].x * a[j].x + a[j].y * a[j].y;
        P += pr;
        S0 += (j & 1)  ? -pr : pr;
        S1 += (j & 2)  ? -pr : pr;
        S2 += (j & 4)  ? -pr : pr;
        S3 += (j & 8)  ? -pr : pr;
        S4 += (j & 16) ? -pr : pr;
    }
    float evq[16];
    #pragma unroll
    for (int q = 0; q < 11; ++q) evq[q] = ((t >> q) & 1) ? -P : P;
    evq[11] = S0; evq[12] = S1; evq[13] = S2; evq[14] = S3; evq[15] = S4;
    #pragma unroll
    for (int q = 0; q < 16; ++q) {
        float v = evq[q];
        #pragma unroll
        for (int o = 32; o >= 1; o >>= 1) v += __shfl_xor(v, o);
        evq[q] = v;
    }
    __shared__ float red[4][16];
    int wave = tid >> 6, lane = tid & 63;
    if (lane == 0) {
        #pragma unroll
        for (int q = 0; q < 16; ++q) red[wave][q] = evq[q];
    }
    __syncthreads();
    if (tid < 16) {
        float v = red[0][tid] + red[1][tid] + red[2][tid] + red[3][tid];
        atomicAdd(&ev[b * 16 + tid], v);
    }
}

// ---------------- kernel 5: head + log_softmax ----------------
__global__ __launch_bounds__(128) void head_kernel(const float* __restrict__ ev,
                                                   const float* __restrict__ fcw,
                                                   const float* __restrict__ fcb,
                                                   float* __restrict__ out) {
    int b = threadIdx.x;
    if (b >= 128) return;
    float e[16];
    #pragma unroll
    for (int q = 0; q < 16; ++q) e[q] = ev[b * 16 + q];
    float lg[16];
    float mx = -1e30f;
    #pragma unroll
    for (int c = 0; c < 16; ++c) {
        float v = fcb[c];
        #pragma unroll
        for (int q = 0; q < 16; ++q) v += e[q] * fcw[c * 16 + q];
        lg[c] = v;
        mx = fmaxf(mx, v);
    }
    float se = 0.f;
    #pragma unroll
    for (int c = 0; c < 16; ++c) se += expf(lg[c] - mx);
    float lse = mx + logf(se);
    #pragma unroll
    for (int c = 0; c < 16; ++c) out[b * 16 + c] = lg[c] - lse;
}

// ---------------- launch ----------------
extern "C" void kernel_launch(void* const* d_in, const int* in_sizes, int n_in,
                              void* d_out, int out_size, void* d_ws, size_t ws_size,
                              hipStream_t stream) {
    const float* x    = (const float*)d_in[0];
    const float* cw   = (const float*)d_in[1];
    const float* cb   = (const float*)d_in[2];
    const float* rot1 = (const float*)d_in[3];
    const float* crx1 = (const float*)d_in[4];
    const float* rot2 = (const float*)d_in[5];
    const float* crx2 = (const float*)d_in[6];
    const float* fcw  = (const float*)d_in[7];
    const float* fcb  = (const float*)d_in[8];

    float* ws    = (float*)d_ws;
    float* p     = ws;                         // 4096
    float* U     = ws + 4096;                  // 2*128*16*16 = 65536 -> ends 69632
    float* crxcs = ws + 69632;                 // 64
    float* ev    = ws + 69696;                 // 2048 -> ends 71744
    float* w0f   = ws + 73728;                 // 16384 -> ends 90112
    f2* seed     = (f2*)(ws + 98304);          // 128*4096 f2 = 4 MiB -> ends 1146880
    unsigned* sbf = (unsigned*)(ws + 1146880); // 128*65536 uint = 32 MiB

    pool_kernel<<<4096, 256, 0, stream>>>(x, p);
    qstep_a0<<<128,  256, 0, stream>>>(p, cw, cb, rot1, crx1, rot2, crx2,
                                       U, crxcs, ev, w0f, seed);
    qstep_a1<<<2048, 256, 0, stream>>>(U, crxcs, w0f, seed, sbf);
    qstep_b1<<<1024, 256, 0, stream>>>(U, crxcs, sbf, ev);
    head_kernel<<<1, 128, 0, stream>>>(ev, fcw, fcb, (float*)d_out);
}

// Round 8
// 57.484 us; speedup vs baseline: 2.1919x; 1.5111x over previous
//
#include <hip/hip_runtime.h>
#include <hip/hip_bf16.h>

typedef float f2 __attribute__((ext_vector_type(2)));

// ---------------- helpers ----------------

// swizzle for 4096-amp f2 LDS tile: XOR low 4 bits with bits 4-7 (bijective)
#define SWZA(i) ((i) ^ (((i) >> 4) & 15))

// complex 2x2 gate on an amplitude pair; u = {u00r,u00i,u01r,u01i,u10r,u10i,u11r,u11i}
__device__ __forceinline__ void gate1q(f2& a0, f2& a1, const float* u) {
    f2 s0 = { -a0.y, a0.x };
    f2 s1 = { -a1.y, a1.x };
    f2 n0 = u[0]*a0 + u[1]*s0 + u[2]*a1 + u[3]*s1;
    f2 n1 = u[4]*a0 + u[5]*s0 + u[6]*a1 + u[7]*s1;
    a0 = n0; a1 = n1;
}

// RX on the (a0,a1) pair: n0 = c*a0 - i*s*a1 ; n1 = -i*s*a0 + c*a1
__device__ __forceinline__ void crx_pair(f2& a0, f2& a1, float c, float s) {
    f2 t0 = { a0.y, -a0.x };
    f2 t1 = { a1.y, -a1.x };
    f2 n0 = c*a0 + s*t1;
    f2 n1 = c*a1 + s*t0;
    a0 = n0; a1 = n1;
}

// plain 1q gate over W-amp window, target bit K
template<int K, int W>
__device__ __forceinline__ void apply1q_win(f2* a, const float* u) {
    #pragma unroll
    for (int m = 0; m < W / 2; ++m) {
        const int j0 = ((m >> K) << (K + 1)) | (m & ((1 << K) - 1));
        gate1q(a[j0], a[j0 | (1 << K)], u);
    }
}

// merged (U_q then CRX(q-1,q)) : control-selected 2x2. u16 = {U | RX*U}
template<int K, int KC, int W>
__device__ __forceinline__ void apply1q_mg(f2* a, const float* u16) {
    #pragma unroll
    for (int m = 0; m < W / 2; ++m) {
        const int j0 = ((m >> K) << (K + 1)) | (m & ((1 << K) - 1));
        const float* uu = u16 + (((j0 >> KC) & 1) << 3);
        gate1q(a[j0], a[j0 | (1 << K)], uu);
    }
}

__device__ __forceinline__ void loadU16(const float* __restrict__ src, float* u) {
    #pragma unroll
    for (int k = 0; k < 16; ++k) u[k] = src[k];
}

// ---------------- kernel 1: adaptive pool ----------------
__global__ __launch_bounds__(256) void pool_kernel(const float* __restrict__ x,
                                                   float* __restrict__ p) {
    int blk = blockIdx.x;            // b*32 + j
    int b = blk >> 5, j = blk & 31;
    int c = j >> 4, dd = (j >> 2) & 3, hh = j & 3;
    const float4* xb = (const float4*)(x + (((size_t)(b * 2 + c) * 16 + dd * 4) << 12)
                                         + (size_t)hh * 1024);
    int tid = threadIdx.x;
    float sum = 0.f;
    #pragma unroll
    for (int k = 0; k < 4; ++k) {
        int f = k * 256 + tid;
        int r = f >> 4, col = f & 15;
        int off = (r >> 4) * 1024 + (r & 15) * 16 + col;
        float4 v = xb[off];
        sum += v.x + v.y + v.z + v.w;
    }
    #pragma unroll
    for (int o = 1; o < 64; o <<= 1) sum += __shfl_xor(sum, o);
    __shared__ float red[4];
    if ((tid & 63) == 0) red[tid >> 6] = sum;
    __syncthreads();
    if (tid == 0) p[blk] = (red[0] + red[1] + red[2] + red[3]) * (1.0f / 4096.0f);
}

// ---------------- kernel 2: fused feats + prep + layer0 passA + right-chains +
//                             layer1 left gates (G0..G10) on the 4 left factors -----
// One block per batch, 256 threads, 64 KB main LDS ([2][4096] f2).
// Outputs: Aout[b][k][t] (k=(c<<1)|j, t bits 0-10), rvg[b][bsel][k][m], crxcs, ev=0.
__global__ __launch_bounds__(256) void qfused(const float* __restrict__ p,
                                              const float* __restrict__ cw,
                                              const float* __restrict__ cb,
                                              const float* __restrict__ rot1,
                                              const float* __restrict__ crx1,
                                              const float* __restrict__ rot2,
                                              const float* __restrict__ crx2,
                                              float* __restrict__ crxcs,
                                              float* __restrict__ ev,
                                              float* __restrict__ rvg,
                                              f2* __restrict__ Aout) {
    __shared__ f2 lds[8192];
    __shared__ float pp[32];
    __shared__ float uL0[12][16];   // layer-0 merged U0..U11
    __shared__ float uB0[4][16];    // layer-0 merged U12..U15
    __shared__ float uL1[11][16];   // layer-1 merged U0..U10
    __shared__ float uR1[5][16];    // layer-1 merged U11..U15
    __shared__ float cs15l0[2];     // layer-0 CRX(15,0) c,s
    int b = blockIdx.x, tid = threadIdx.x;

    if (tid < 32) pp[tid] = p[b * 32 + tid];
    __syncthreads();
    if (tid >= 16 && tid < 32) ev[b * 16 + (tid - 16)] = 0.f;
    if (tid < 16) {
        int q = tid;
        float f = cb[q];
        #pragma unroll
        for (int jj = 0; jj < 32; ++jj) f += pp[jj] * cw[q * 32 + jj];
        float cr = cosf(0.5f * f), sr = sinf(0.5f * f);
        #pragma unroll
        for (int l = 0; l < 2; ++l) {
            const float* rw = (l == 0 ? rot1 : rot2) + q * 3;
            float phi = rw[0], th = rw[1], om = rw[2];
            float ct = cosf(0.5f * th), st = sinf(0.5f * th);
            float aa = 0.5f * (phi + om), dd = 0.5f * (phi - om);
            float ca = cosf(aa), sa = sinf(aa), cd = cosf(dd), sd = sinf(dd);
            float R00r =  ct * ca, R00i = -ct * sa;
            float R01r = -st * cd, R01i = -st * sd;
            float R10r =  st * cd, R10i = -st * sd;
            float R11r =  ct * ca, R11i =  ct * sa;
            float u0 = cr * R00r + sr * R01i;
            float u1 = cr * R00i - sr * R01r;
            float u2 = cr * R01r + sr * R00i;
            float u3 = cr * R01i - sr * R00r;
            float u4 = cr * R10r + sr * R11i;
            float u5 = cr * R10i - sr * R11r;
            float u6 = cr * R11r + sr * R10i;
            float u7 = cr * R11i - sr * R10r;
            float g[16];
            g[0] = u0; g[1] = u1; g[2] = u2; g[3] = u3;
            g[4] = u4; g[5] = u5; g[6] = u6; g[7] = u7;
            if (q >= 1) {
                float thc = (l == 0 ? crx1 : crx2)[q - 1];
                float c2 = cosf(0.5f * thc), s2 = sinf(0.5f * thc);
                g[8]  = c2*u0 + s2*u5;  g[9]  = c2*u1 - s2*u4;
                g[10] = c2*u2 + s2*u7;  g[11] = c2*u3 - s2*u6;
                g[12] = c2*u4 + s2*u1;  g[13] = c2*u5 - s2*u0;
                g[14] = c2*u6 + s2*u3;  g[15] = c2*u7 - s2*u2;
            } else {
                #pragma unroll
                for (int k = 0; k < 8; ++k) g[8 + k] = g[k];
            }
            float* s = (l == 0) ? ((q < 12) ? uL0[q] : uB0[q - 12])
                                : ((q < 11) ? uL1[q] : uR1[q - 11]);
            #pragma unroll
            for (int k = 0; k < 16; ++k) s[k] = g[k];
            float th2 = (l == 0 ? crx1 : crx2)[q];
            float cc = cosf(0.5f * th2), ss = sinf(0.5f * th2);
            if (l == 0 && q == 15) { cs15l0[0] = cc; cs15l0[1] = ss; }
            if (b == 0) {
                crxcs[(l * 16 + q) * 2 + 0] = cc;
                crxcs[(l * 16 + q) * 2 + 1] = ss;
            }
        }
    }
    __syncthreads();

    // ---- right chains: 8 threads, one per (j, c, bsel) ----
    // R'_{(j,c)}^{(bsel)} = G15..G12 * G11^{(bsel)} * mask_c(W0col_j)
    if (tid >= 32 && tid < 40) {
        int idx = tid - 32;
        int j = idx & 1, c = (idx >> 1) & 1, bsel = (idx >> 2) & 1;
        f2 w[32];
        #pragma unroll
        for (int m = 0; m < 32; ++m) w[m] = f2{0.f, 0.f};
        w[j] = f2{1.f, 0.f};
        // layer-0 pass B window (merged U12..U15 incl CRX(11,12)..(14,15))
        apply1q_mg<1, 0, 32>(w, uB0[0]);
        apply1q_mg<2, 1, 32>(w, uB0[1]);
        apply1q_mg<3, 2, 32>(w, uB0[2]);
        apply1q_mg<4, 3, 32>(w, uB0[3]);
        // mask by final bit 15 (m bit 4) = c  (layer-0 CRX(15,0) split)
        #pragma unroll
        for (int m = 0; m < 32; ++m)
            if (((m >> 4) & 1) != c) w[m] = f2{0.f, 0.f};
        // G11^{(bsel)}: U11 (bsel=0) or RX(th10,11)*U11 (bsel=1) on m-bit 0
        #pragma unroll
        for (int mm = 0; mm < 32; mm += 2)
            gate1q(w[mm], w[mm + 1], uR1[0] + (bsel << 3));
        // G12..G15 (merged right gates)
        apply1q_mg<1, 0, 32>(w, uR1[1]);
        apply1q_mg<2, 1, 32>(w, uR1[2]);
        apply1q_mg<3, 2, 32>(w, uR1[3]);
        apply1q_mg<4, 3, 32>(w, uR1[4]);
        int k = (c << 1) | j;
        float* d = rvg + (((size_t)(b * 2 + bsel) * 4 + k) * 32) * 2;
        #pragma unroll
        for (int m = 0; m < 32; ++m) { d[2 * m] = w[m].x; d[2 * m + 1] = w[m].y; }
    }

    // ---- layer-0 pass A on e_0 (bits 0-11, merged gates U0..U11) -> lds half0 ----
    #pragma unroll
    for (int j = 0; j < 16; ++j) lds[SWZA(j * 256 + tid)] = f2{0.f, 0.f};
    if (tid == 0) lds[SWZA(0)] = f2{1.f, 0.f};
    __syncthreads();

    {
        f2 a[16];
        // SR1: bits 0..3
        #pragma unroll
        for (int j = 0; j < 16; ++j) a[j] = lds[SWZA((tid << 4) | j)];
        apply1q_win<0, 16>(a, uL0[0]);
        apply1q_mg<1, 0, 16>(a, uL0[1]);
        apply1q_mg<2, 1, 16>(a, uL0[2]);
        apply1q_mg<3, 2, 16>(a, uL0[3]);
        #pragma unroll
        for (int j = 0; j < 16; ++j) lds[SWZA((tid << 4) | j)] = a[j];
        __syncthreads();
        // SR2: bits 3..6
        int lo = tid & 7, hi = (tid >> 3) << 7;
        #pragma unroll
        for (int j = 0; j < 16; ++j) a[j] = lds[SWZA(lo | (j << 3) | hi)];
        apply1q_mg<1, 0, 16>(a, uL0[4]);
        apply1q_mg<2, 1, 16>(a, uL0[5]);
        apply1q_mg<3, 2, 16>(a, uL0[6]);
        #pragma unroll
        for (int j = 0; j < 16; ++j) lds[SWZA(lo | (j << 3) | hi)] = a[j];
        __syncthreads();
        // SR3: bits 6..9
        int lo2 = tid & 63, hi2 = (tid >> 6) << 10;
        #pragma unroll
        for (int j = 0; j < 16; ++j) a[j] = lds[SWZA(lo2 | (j << 6) | hi2)];
        apply1q_mg<1, 0, 16>(a, uL0[7]);
        apply1q_mg<2, 1, 16>(a, uL0[8]);
        apply1q_mg<3, 2, 16>(a, uL0[9]);
        #pragma unroll
        for (int j = 0; j < 16; ++j) lds[SWZA(lo2 | (j << 6) | hi2)] = a[j];
        __syncthreads();
        // SR4: bits 8..11
        #pragma unroll
        for (int j = 0; j < 16; ++j) a[j] = lds[SWZA(tid | (j << 8))];
        apply1q_mg<2, 1, 16>(a, uL0[10]);
        apply1q_mg<3, 2, 16>(a, uL0[11]);
        #pragma unroll
        for (int j = 0; j < 16; ++j) lds[SWZA(tid | (j << 8))] = a[j];
        __syncthreads();
    }

    // ---- layer-1 left gates G0..G10 on 4 left factors (u_j and v_j = RX0 u_j) ----
    float g[16];
    f2 a[32];
    // R1: window bits 0-4 ; thread = (vv, j, outer = t bits 5-10)
    {
        int vv = tid >> 7, j = (tid >> 6) & 1, outer = tid & 63;
        int base = (j << 11) | (outer << 5);
        #pragma unroll
        for (int w = 0; w < 32; ++w) a[w] = lds[SWZA(base | w)];   // read u (half0)
        __syncthreads();   // all reads of half0 done before half0 is overwritten
        if (vv) {          // v = RX0(theta15_L0) u : bit 0 = window bit 0
            float c = cs15l0[0], s = cs15l0[1];
            #pragma unroll
            for (int w = 0; w < 32; w += 2) crx_pair(a[w], a[w + 1], c, s);
        }
        loadU16(uL1[0], g);  apply1q_win<0, 32>(a, g);      // G0
        loadU16(uL1[1], g);  apply1q_mg<1, 0, 32>(a, g);    // G1
        loadU16(uL1[2], g);  apply1q_mg<2, 1, 32>(a, g);    // G2
        loadU16(uL1[3], g);  apply1q_mg<3, 2, 32>(a, g);    // G3
        loadU16(uL1[4], g);  apply1q_mg<4, 3, 32>(a, g);    // G4
        #pragma unroll
        for (int w = 0; w < 32; ++w) lds[(vv << 12) | SWZA(base | w)] = a[w];
    }
    __syncthreads();
    // R2: window bits 4-8 ; thread = (vv, j, b910 = bits 9-10, b03 = bits 0-3)
    {
        int vv = tid >> 7, j = (tid >> 6) & 1, b910 = (tid >> 4) & 3, b03 = tid & 15;
        int base = (j << 11) | (b910 << 9) | b03;
        #pragma unroll
        for (int w = 0; w < 32; ++w) a[w] = lds[(vv << 12) | SWZA(base | (w << 4))];
        loadU16(uL1[5], g);  apply1q_mg<1, 0, 32>(a, g);    // G5
        loadU16(uL1[6], g);  apply1q_mg<2, 1, 32>(a, g);    // G6
        loadU16(uL1[7], g);  apply1q_mg<3, 2, 32>(a, g);    // G7
        loadU16(uL1[8], g);  apply1q_mg<4, 3, 32>(a, g);    // G8
        #pragma unroll
        for (int w = 0; w < 32; ++w) lds[(vv << 12) | SWZA(base | (w << 4))] = a[w];
    }
    __syncthreads();
    // R3: window bits 6-10 ; thread = (vv, j, b05 = bits 0-5) ; store A to global
    {
        int vv = tid >> 7, j = (tid >> 6) & 1, b05 = tid & 63;
        int base = (j << 11) | b05;
        #pragma unroll
        for (int w = 0; w < 32; ++w) a[w] = lds[(vv << 12) | SWZA(base | (w << 6))];
        loadU16(uL1[9], g);   apply1q_mg<3, 2, 32>(a, g);   // G9
        loadU16(uL1[10], g);  apply1q_mg<4, 3, 32>(a, g);   // G10
        int k = (vv << 1) | j;
        f2* Ao = Aout + ((size_t)(b * 4 + k) << 11) + b05;
        #pragma unroll
        for (int w = 0; w < 32; ++w) Ao[w << 6] = a[w];
    }
}

// ---------------- kernel 3: rank-4 expansion + CRX(15,0) + EV reduce ----------------
// grid: 1024 (b = blk>>3, part = blk&7) ; 256 threads ; t = part*256+tid (bits 0-10)
__global__ __launch_bounds__(256) void qev(const float* __restrict__ crxcs,
                                           const float* __restrict__ rvg,
                                           const f2* __restrict__ Aout,
                                           float* __restrict__ ev) {
    int tid = threadIdx.x;
    int b = blockIdx.x >> 3, part = blockIdx.x & 7;
    int t = part * 256 + tid;
    int bsel = (part >> 2) & 1;          // bit 10 of t (block-uniform)

    f2 A[4], sA[4];
    #pragma unroll
    for (int k = 0; k < 4; ++k) {
        A[k] = Aout[((size_t)(b * 4 + k) << 11) + t];
        sA[k] = f2{ -A[k].y, A[k].x };
    }
    const float* rb = rvg + ((size_t)(b * 2 + bsel) * 4 * 32) * 2;  // [k][m] interleaved

    f2 a[32];
    #pragma unroll
    for (int m = 0; m < 32; ++m) {
        f2 ac = rb[(0 * 32 + m) * 2] * A[0] + rb[(0 * 32 + m) * 2 + 1] * sA[0];
        ac    += rb[(1 * 32 + m) * 2] * A[1] + rb[(1 * 32 + m) * 2 + 1] * sA[1];
        ac    += rb[(2 * 32 + m) * 2] * A[2] + rb[(2 * 32 + m) * 2 + 1] * sA[2];
        ac    += rb[(3 * 32 + m) * 2] * A[3] + rb[(3 * 32 + m) * 2 + 1] * sA[3];
        a[m] = ac;
    }

    {   // layer-1 CRX(15,0): control = m bit 4, target = t bit 0 = lane bit 0
        float c = crxcs[32 + 30], s = crxcs[32 + 31];
        #pragma unroll
        for (int m = 16; m < 32; ++m) {
            float pr = __shfl_xor(a[m].x, 1);
            float pi = __shfl_xor(a[m].y, 1);
            float nr = c * a[m].x + s * pi;
            float ni = c * a[m].y - s * pr;
            a[m].x = nr; a[m].y = ni;
        }
    }

    float P = 0.f, S0 = 0.f, S1 = 0.f, S2 = 0.f, S3 = 0.f, S4 = 0.f;
    #pragma unroll
    for (int m = 0; m < 32; ++m) {
        float pr = a[m].x * a[m].x + a[m].y * a[m].y;
        P += pr;
        S0 += (m & 1)  ? -pr : pr;
        S1 += (m & 2)  ? -pr : pr;
        S2 += (m & 4)  ? -pr : pr;
        S3 += (m & 8)  ? -pr : pr;
        S4 += (m & 16) ? -pr : pr;
    }
    float evq[16];
    #pragma unroll
    for (int q = 0; q < 11; ++q) evq[q] = ((t >> q) & 1) ? -P : P;
    evq[11] = S0; evq[12] = S1; evq[13] = S2; evq[14] = S3; evq[15] = S4;
    #pragma unroll
    for (int q = 0; q < 16; ++q) {
        float v = evq[q];
        #pragma unroll
        for (int o = 32; o >= 1; o >>= 1) v += __shfl_xor(v, o);
        evq[q] = v;
    }
    __shared__ float red[4][16];
    int wave = tid >> 6, lane = tid & 63;
    if (lane == 0) {
        #pragma unroll
        for (int q = 0; q < 16; ++q) red[wave][q] = evq[q];
    }
    __syncthreads();
    if (tid < 16) {
        float v = red[0][tid] + red[1][tid] + red[2][tid] + red[3][tid];
        atomicAdd(&ev[b * 16 + tid], v);
    }
}

// ---------------- kernel 4: head + log_softmax ----------------
__global__ __launch_bounds__(128) void head_kernel(const float* __restrict__ ev,
                                                   const float* __restrict__ fcw,
                                                   const float* __restrict__ fcb,
                                                   float* __restrict__ out) {
    int b = threadIdx.x;
    if (b >= 128) return;
    float e[16];
    #pragma unroll
    for (int q = 0; q < 16; ++q) e[q] = ev[b * 16 + q];
    float lg[16];
    float mx = -1e30f;
    #pragma unroll
    for (int c = 0; c < 16; ++c) {
        float v = fcb[c];
        #pragma unroll
        for (int q = 0; q < 16; ++q) v += e[q] * fcw[c * 16 + q];
        lg[c] = v;
        mx = fmaxf(mx, v);
    }
    float se = 0.f;
    #pragma unroll
    for (int c = 0; c < 16; ++c) se += expf(lg[c] - mx);
    float lse = mx + logf(se);
    #pragma unroll
    for (int c = 0; c < 16; ++c) out[b * 16 + c] = lg[c] - lse;
}

// ---------------- launch ----------------
extern "C" void kernel_launch(void* const* d_in, const int* in_sizes, int n_in,
                              void* d_out, int out_size, void* d_ws, size_t ws_size,
                              hipStream_t stream) {
    const float* x    = (const float*)d_in[0];
    const float* cw   = (const float*)d_in[1];
    const float* cb   = (const float*)d_in[2];
    const float* rot1 = (const float*)d_in[3];
    const float* crx1 = (const float*)d_in[4];
    const float* rot2 = (const float*)d_in[5];
    const float* crx2 = (const float*)d_in[6];
    const float* fcw  = (const float*)d_in[7];
    const float* fcb  = (const float*)d_in[8];

    float* ws    = (float*)d_ws;
    float* p     = ws;                     // 4096 floats
    float* crxcs = ws + 4096;              // 64
    float* ev    = ws + 8192;              // 2048
    float* rvg   = ws + 16384;             // 128*2*4*32*2 = 65536 -> ends 81920
    f2* Aout     = (f2*)(ws + 81920);      // 128*4*2048 f2 = 8 MiB

    pool_kernel<<<4096, 256, 0, stream>>>(x, p);
    qfused<<<128, 256, 0, stream>>>(p, cw, cb, rot1, crx1, rot2, crx2,
                                    crxcs, ev, rvg, Aout);
    qev<<<1024, 256, 0, stream>>>(crxcs, rvg, Aout, ev);
    head_kernel<<<1, 128, 0, stream>>>(ev, fcw, fcb, (float*)d_out);
}

// Round 9
// 51.770 us; speedup vs baseline: 2.4338x; 1.1104x over previous
//
#include <hip/hip_runtime.h>
#include <hip/hip_bf16.h>

typedef float f2 __attribute__((ext_vector_type(2)));

// ---------------- helpers ----------------

// swizzle for 4096-amp f2 LDS tile: XOR low 4 bits with bits 4-7 (bijective)
#define SWZA(i) ((i) ^ (((i) >> 4) & 15))

// complex 2x2 gate on an amplitude pair; u = {u00r,u00i,u01r,u01i,u10r,u10i,u11r,u11i}
__device__ __forceinline__ void gate1q(f2& a0, f2& a1, const float* u) {
    f2 s0 = { -a0.y, a0.x };
    f2 s1 = { -a1.y, a1.x };
    f2 n0 = u[0]*a0 + u[1]*s0 + u[2]*a1 + u[3]*s1;
    f2 n1 = u[4]*a0 + u[5]*s0 + u[6]*a1 + u[7]*s1;
    a0 = n0; a1 = n1;
}

// RX on the (a0,a1) pair: n0 = c*a0 - i*s*a1 ; n1 = -i*s*a0 + c*a1
__device__ __forceinline__ void crx_pair(f2& a0, f2& a1, float c, float s) {
    f2 t0 = { a0.y, -a0.x };
    f2 t1 = { a1.y, -a1.x };
    f2 n0 = c*a0 + s*t1;
    f2 n1 = c*a1 + s*t0;
    a0 = n0; a1 = n1;
}

// plain 1q gate over W-amp window, target bit K
template<int K, int W>
__device__ __forceinline__ void apply1q_win(f2* a, const float* u) {
    #pragma unroll
    for (int m = 0; m < W / 2; ++m) {
        const int j0 = ((m >> K) << (K + 1)) | (m & ((1 << K) - 1));
        gate1q(a[j0], a[j0 | (1 << K)], u);
    }
}

// merged (U_q then CRX(q-1,q)) : control-selected 2x2. u16 = {U | RX*U}
template<int K, int KC, int W>
__device__ __forceinline__ void apply1q_mg(f2* a, const float* u16) {
    #pragma unroll
    for (int m = 0; m < W / 2; ++m) {
        const int j0 = ((m >> K) << (K + 1)) | (m & ((1 << K) - 1));
        const float* uu = u16 + (((j0 >> KC) & 1) << 3);
        gate1q(a[j0], a[j0 | (1 << K)], uu);
    }
}

__device__ __forceinline__ void loadU16(const float* __restrict__ src, float* u) {
    #pragma unroll
    for (int k = 0; k < 16; ++k) u[k] = src[k];
}

// ---------------- kernel 1: adaptive pool ----------------
__global__ __launch_bounds__(256) void pool_kernel(const float* __restrict__ x,
                                                   float* __restrict__ p) {
    int blk = blockIdx.x;            // b*32 + j
    int b = blk >> 5, j = blk & 31;
    int c = j >> 4, dd = (j >> 2) & 3, hh = j & 3;
    const float4* xb = (const float4*)(x + (((size_t)(b * 2 + c) * 16 + dd * 4) << 12)
                                         + (size_t)hh * 1024);
    int tid = threadIdx.x;
    float sum = 0.f;
    #pragma unroll
    for (int k = 0; k < 4; ++k) {
        int f = k * 256 + tid;
        int r = f >> 4, col = f & 15;
        int off = (r >> 4) * 1024 + (r & 15) * 16 + col;
        float4 v = xb[off];
        sum += v.x + v.y + v.z + v.w;
    }
    #pragma unroll
    for (int o = 1; o < 64; o <<= 1) sum += __shfl_xor(sum, o);
    __shared__ float red[4];
    if ((tid & 63) == 0) red[tid >> 6] = sum;
    __syncthreads();
    if (tid == 0) p[blk] = (red[0] + red[1] + red[2] + red[3]) * (1.0f / 4096.0f);
}

// ---------------- kernel 2: fused feats + prep + layer0 passA + right-chains +
//                  layer1 left gates (G0..G10) on this block's 2 left factors ------
// grid = 256: b = blk>>1, vv = blk&1. 256 threads, 64 KB main LDS ([2][4096] f2).
// passA (dup across vv) -> lds[0..4095]; left gates in 4x 4-bit-window rounds at
// 16 amps/thread on factors k=(vv<<1)|j -> Aout[b][k][t].
__global__ __launch_bounds__(256) void qfused(const float* __restrict__ p,
                                              const float* __restrict__ cw,
                                              const float* __restrict__ cb,
                                              const float* __restrict__ rot1,
                                              const float* __restrict__ crx1,
                                              const float* __restrict__ rot2,
                                              const float* __restrict__ crx2,
                                              float* __restrict__ crxcs,
                                              float* __restrict__ ev,
                                              float* __restrict__ rvg,
                                              f2* __restrict__ Aout) {
    __shared__ f2 lds[8192];
    __shared__ float pp[32];
    __shared__ float uL0[12][16];   // layer-0 merged U0..U11
    __shared__ float uB0[4][16];    // layer-0 merged U12..U15
    __shared__ float uL1[11][16];   // layer-1 merged U0..U10
    __shared__ float uR1[5][16];    // layer-1 merged U11..U15
    __shared__ float cs15l0[2];     // layer-0 CRX(15,0) c,s
    int b = blockIdx.x >> 1, vv = blockIdx.x & 1, tid = threadIdx.x;

    if (tid < 32) pp[tid] = p[b * 32 + tid];
    __syncthreads();
    if (tid >= 16 && tid < 32) ev[b * 16 + (tid - 16)] = 0.f;
    if (tid < 16) {
        int q = tid;
        float f = cb[q];
        #pragma unroll
        for (int jj = 0; jj < 32; ++jj) f += pp[jj] * cw[q * 32 + jj];
        float cr = cosf(0.5f * f), sr = sinf(0.5f * f);
        #pragma unroll
        for (int l = 0; l < 2; ++l) {
            const float* rw = (l == 0 ? rot1 : rot2) + q * 3;
            float phi = rw[0], th = rw[1], om = rw[2];
            float ct = cosf(0.5f * th), st = sinf(0.5f * th);
            float aa = 0.5f * (phi + om), dd = 0.5f * (phi - om);
            float ca = cosf(aa), sa = sinf(aa), cd = cosf(dd), sd = sinf(dd);
            float R00r =  ct * ca, R00i = -ct * sa;
            float R01r = -st * cd, R01i = -st * sd;
            float R10r =  st * cd, R10i = -st * sd;
            float R11r =  ct * ca, R11i =  ct * sa;
            float u0 = cr * R00r + sr * R01i;
            float u1 = cr * R00i - sr * R01r;
            float u2 = cr * R01r + sr * R00i;
            float u3 = cr * R01i - sr * R00r;
            float u4 = cr * R10r + sr * R11i;
            float u5 = cr * R10i - sr * R11r;
            float u6 = cr * R11r + sr * R10i;
            float u7 = cr * R11i - sr * R10r;
            float g[16];
            g[0] = u0; g[1] = u1; g[2] = u2; g[3] = u3;
            g[4] = u4; g[5] = u5; g[6] = u6; g[7] = u7;
            if (q >= 1) {
                float thc = (l == 0 ? crx1 : crx2)[q - 1];
                float c2 = cosf(0.5f * thc), s2 = sinf(0.5f * thc);
                g[8]  = c2*u0 + s2*u5;  g[9]  = c2*u1 - s2*u4;
                g[10] = c2*u2 + s2*u7;  g[11] = c2*u3 - s2*u6;
                g[12] = c2*u4 + s2*u1;  g[13] = c2*u5 - s2*u0;
                g[14] = c2*u6 + s2*u3;  g[15] = c2*u7 - s2*u2;
            } else {
                #pragma unroll
                for (int k = 0; k < 8; ++k) g[8 + k] = g[k];
            }
            float* s = (l == 0) ? ((q < 12) ? uL0[q] : uB0[q - 12])
                                : ((q < 11) ? uL1[q] : uR1[q - 11]);
            #pragma unroll
            for (int k = 0; k < 16; ++k) s[k] = g[k];
            float th2 = (l == 0 ? crx1 : crx2)[q];
            float cc = cosf(0.5f * th2), ss = sinf(0.5f * th2);
            if (l == 0 && q == 15) { cs15l0[0] = cc; cs15l0[1] = ss; }
            if (b == 0) {
                crxcs[(l * 16 + q) * 2 + 0] = cc;
                crxcs[(l * 16 + q) * 2 + 1] = ss;
            }
        }
    }
    __syncthreads();

    // ---- right chains: 8 threads, one per (j, c, bsel) (dup across vv, benign) ----
    if (tid >= 32 && tid < 40) {
        int idx = tid - 32;
        int j = idx & 1, c = (idx >> 1) & 1, bsel = (idx >> 2) & 1;
        f2 w[32];
        #pragma unroll
        for (int m = 0; m < 32; ++m) w[m] = f2{0.f, 0.f};
        w[j] = f2{1.f, 0.f};
        apply1q_mg<1, 0, 32>(w, uB0[0]);
        apply1q_mg<2, 1, 32>(w, uB0[1]);
        apply1q_mg<3, 2, 32>(w, uB0[2]);
        apply1q_mg<4, 3, 32>(w, uB0[3]);
        #pragma unroll
        for (int m = 0; m < 32; ++m)
            if (((m >> 4) & 1) != c) w[m] = f2{0.f, 0.f};
        #pragma unroll
        for (int mm = 0; mm < 32; mm += 2)
            gate1q(w[mm], w[mm + 1], uR1[0] + (bsel << 3));
        apply1q_mg<1, 0, 32>(w, uR1[1]);
        apply1q_mg<2, 1, 32>(w, uR1[2]);
        apply1q_mg<3, 2, 32>(w, uR1[3]);
        apply1q_mg<4, 3, 32>(w, uR1[4]);
        int k = (c << 1) | j;
        float* d = rvg + (((size_t)(b * 2 + bsel) * 4 + k) * 32) * 2;
        #pragma unroll
        for (int m = 0; m < 32; ++m) { d[2 * m] = w[m].x; d[2 * m + 1] = w[m].y; }
    }

    // ---- layer-0 pass A on e_0 (bits 0-11, merged gates U0..U11) -> lds[0..4095] ---
    #pragma unroll
    for (int j = 0; j < 16; ++j) lds[SWZA(j * 256 + tid)] = f2{0.f, 0.f};
    if (tid == 0) lds[SWZA(0)] = f2{1.f, 0.f};
    __syncthreads();

    {
        f2 a[16];
        // SR1: bits 0..3
        #pragma unroll
        for (int j = 0; j < 16; ++j) a[j] = lds[SWZA((tid << 4) | j)];
        apply1q_win<0, 16>(a, uL0[0]);
        apply1q_mg<1, 0, 16>(a, uL0[1]);
        apply1q_mg<2, 1, 16>(a, uL0[2]);
        apply1q_mg<3, 2, 16>(a, uL0[3]);
        #pragma unroll
        for (int j = 0; j < 16; ++j) lds[SWZA((tid << 4) | j)] = a[j];
        __syncthreads();
        // SR2: bits 3..6
        int lo = tid & 7, hi = (tid >> 3) << 7;
        #pragma unroll
        for (int j = 0; j < 16; ++j) a[j] = lds[SWZA(lo | (j << 3) | hi)];
        apply1q_mg<1, 0, 16>(a, uL0[4]);
        apply1q_mg<2, 1, 16>(a, uL0[5]);
        apply1q_mg<3, 2, 16>(a, uL0[6]);
        #pragma unroll
        for (int j = 0; j < 16; ++j) lds[SWZA(lo | (j << 3) | hi)] = a[j];
        __syncthreads();
        // SR3: bits 6..9
        int lo2 = tid & 63, hi2 = (tid >> 6) << 10;
        #pragma unroll
        for (int j = 0; j < 16; ++j) a[j] = lds[SWZA(lo2 | (j << 6) | hi2)];
        apply1q_mg<1, 0, 16>(a, uL0[7]);
        apply1q_mg<2, 1, 16>(a, uL0[8]);
        apply1q_mg<3, 2, 16>(a, uL0[9]);
        #pragma unroll
        for (int j = 0; j < 16; ++j) lds[SWZA(lo2 | (j << 6) | hi2)] = a[j];
        __syncthreads();
        // SR4: bits 8..11
        #pragma unroll
        for (int j = 0; j < 16; ++j) a[j] = lds[SWZA(tid | (j << 8))];
        apply1q_mg<2, 1, 16>(a, uL0[10]);
        apply1q_mg<3, 2, 16>(a, uL0[11]);
        #pragma unroll
        for (int j = 0; j < 16; ++j) lds[SWZA(tid | (j << 8))] = a[j];
        __syncthreads();
    }

    // ---- layer-1 left gates G0..G10, this block's vv, factors j=0,1 -------------
    // u_j(t) = passA[(j<<11)|t]; vv=1 applies RX0(theta15_L0) on t-bit0 first.
    // 4 rounds, 16 amps/thread; working tile in lds[4096..8191].
    float g[16];
    f2 a[16];
    // R1: window t bits 0-3 ; thread = (j = tid>>7, outer = tid&127 -> t bits 4-10)
    {
        int j = tid >> 7, outer = tid & 127;
        int base = (j << 11) | (outer << 4);
        #pragma unroll
        for (int w = 0; w < 16; ++w) a[w] = lds[SWZA(base | w)];
        if (vv) {
            float c = cs15l0[0], s = cs15l0[1];
            #pragma unroll
            for (int w = 0; w < 16; w += 2) crx_pair(a[w], a[w + 1], c, s);
        }
        loadU16(uL1[0], g);  apply1q_win<0, 16>(a, g);      // G0
        loadU16(uL1[1], g);  apply1q_mg<1, 0, 16>(a, g);    // G1
        loadU16(uL1[2], g);  apply1q_mg<2, 1, 16>(a, g);    // G2
        loadU16(uL1[3], g);  apply1q_mg<3, 2, 16>(a, g);    // G3
        #pragma unroll
        for (int w = 0; w < 16; ++w) lds[4096 + SWZA(base | w)] = a[w];
    }
    __syncthreads();
    // R2: window t bits 3-6 ; t bits 0-2 = tid&7, bits 7-10 = (tid>>3)&15
    {
        int j = tid >> 7;
        int base = (j << 11) | (((tid >> 3) & 15) << 7) | (tid & 7);
        #pragma unroll
        for (int w = 0; w < 16; ++w) a[w] = lds[4096 + SWZA(base | (w << 3))];
        loadU16(uL1[4], g);  apply1q_mg<1, 0, 16>(a, g);    // G4
        loadU16(uL1[5], g);  apply1q_mg<2, 1, 16>(a, g);    // G5
        loadU16(uL1[6], g);  apply1q_mg<3, 2, 16>(a, g);    // G6
        #pragma unroll
        for (int w = 0; w < 16; ++w) lds[4096 + SWZA(base | (w << 3))] = a[w];
    }
    __syncthreads();
    // R3: window t bits 6-9 ; t bits 0-5 = tid&63, bit 10 = (tid>>6)&1
    {
        int j = tid >> 7;
        int base = (j << 11) | (((tid >> 6) & 1) << 10) | (tid & 63);
        #pragma unroll
        for (int w = 0; w < 16; ++w) a[w] = lds[4096 + SWZA(base | (w << 6))];
        loadU16(uL1[7], g);  apply1q_mg<1, 0, 16>(a, g);    // G7
        loadU16(uL1[8], g);  apply1q_mg<2, 1, 16>(a, g);    // G8
        loadU16(uL1[9], g);  apply1q_mg<3, 2, 16>(a, g);    // G9
        #pragma unroll
        for (int w = 0; w < 16; ++w) lds[4096 + SWZA(base | (w << 6))] = a[w];
    }
    __syncthreads();
    // R4: window t bits 7-10 ; t bits 0-6 = tid&127 ; store A to global
    {
        int j = tid >> 7, lo = tid & 127;
        int base = (j << 11) | lo;
        #pragma unroll
        for (int w = 0; w < 16; ++w) a[w] = lds[4096 + SWZA(base | (w << 7))];
        loadU16(uL1[10], g);  apply1q_mg<3, 2, 16>(a, g);   // G10 (t10=bit3, c9=bit2)
        int k = (vv << 1) | j;
        f2* Ao = Aout + ((size_t)(b * 4 + k) << 11);
        #pragma unroll
        for (int w = 0; w < 16; ++w) Ao[(w << 7) | lo] = a[w];
    }
}

// ---------------- kernel 3: rank-4 expansion + CRX(15,0) + EV reduce (WHT) ----------
// grid: 1024 (b = blk>>3, part = blk&7) ; 256 threads ; t = part*256+tid (bits 0-10)
__global__ __launch_bounds__(256) void qev(const float* __restrict__ crxcs,
                                           const float* __restrict__ rvg,
                                           const f2* __restrict__ Aout,
                                           float* __restrict__ ev) {
    int tid = threadIdx.x;
    int b = blockIdx.x >> 3, part = blockIdx.x & 7;
    int t = part * 256 + tid;
    int bsel = (part >> 2) & 1;          // bit 10 of t (block-uniform)

    f2 A[4], sA[4];
    #pragma unroll
    for (int k = 0; k < 4; ++k) {
        A[k] = Aout[((size_t)(b * 4 + k) << 11) + t];
        sA[k] = f2{ -A[k].y, A[k].x };
    }
    const float* rb = rvg + ((size_t)(b * 2 + bsel) * 4 * 32) * 2;  // [k][m] interleaved

    f2 a[32];
    #pragma unroll
    for (int m = 0; m < 32; ++m) {
        f2 ac = rb[(0 * 32 + m) * 2] * A[0] + rb[(0 * 32 + m) * 2 + 1] * sA[0];
        ac    += rb[(1 * 32 + m) * 2] * A[1] + rb[(1 * 32 + m) * 2 + 1] * sA[1];
        ac    += rb[(2 * 32 + m) * 2] * A[2] + rb[(2 * 32 + m) * 2 + 1] * sA[2];
        ac    += rb[(3 * 32 + m) * 2] * A[3] + rb[(3 * 32 + m) * 2 + 1] * sA[3];
        a[m] = ac;
    }

    {   // layer-1 CRX(15,0): control = m bit 4, target = t bit 0 = lane bit 0
        float c = crxcs[32 + 30], s = crxcs[32 + 31];
        #pragma unroll
        for (int m = 16; m < 32; ++m) {
            float pr = __shfl_xor(a[m].x, 1);
            float pi = __shfl_xor(a[m].y, 1);
            float nr = c * a[m].x + s * pi;
            float ni = c * a[m].y - s * pr;
            a[m].x = nr; a[m].y = ni;
        }
    }

    float P = 0.f, S0 = 0.f, S1 = 0.f, S2 = 0.f, S3 = 0.f, S4 = 0.f;
    #pragma unroll
    for (int m = 0; m < 32; ++m) {
        float pr = a[m].x * a[m].x + a[m].y * a[m].y;
        P += pr;
        S0 += (m & 1)  ? -pr : pr;
        S1 += (m & 2)  ? -pr : pr;
        S2 += (m & 4)  ? -pr : pr;
        S3 += (m & 8)  ? -pr : pr;
        S4 += (m & 16) ? -pr : pr;
    }

    // ---- WHT over 6 lane bits for P (gives all t-bit-signed sums); plain sums for S*
    int lane = tid & 63, wave = tid >> 6;
    #pragma unroll
    for (int o = 1; o < 64; o <<= 1) {
        float tP = __shfl_xor(P, o);
        P = (lane & o) ? (tP - P) : (P + tP);
        S0 += __shfl_xor(S0, o);
        S1 += __shfl_xor(S1, o);
        S2 += __shfl_xor(S2, o);
        S3 += __shfl_xor(S3, o);
        S4 += __shfl_xor(S4, o);
    }
    __shared__ float red[4][12];
    if ((lane & (lane - 1)) == 0) {       // lanes 0,1,2,4,8,16,32
        int slot = (lane == 0) ? 0 : (31 - __clz((unsigned)lane)) + 1;  // 1..6
        red[wave][slot] = P;
    }
    if (lane == 0) {
        red[wave][7] = S0; red[wave][8] = S1; red[wave][9] = S2;
        red[wave][10] = S3; red[wave][11] = S4;
    }
    __syncthreads();
    if (tid < 16) {
        int q = tid;
        float v;
        if (q < 6)       v = red[0][1+q] + red[1][1+q] + red[2][1+q] + red[3][1+q];
        else if (q == 6) v = red[0][0] - red[1][0] + red[2][0] - red[3][0];   // t6 = wave bit 0
        else if (q == 7) v = red[0][0] + red[1][0] - red[2][0] - red[3][0];   // t7 = wave bit 1
        else if (q < 11) {
            v = red[0][0] + red[1][0] + red[2][0] + red[3][0];
            if ((part >> (q - 8)) & 1) v = -v;                                 // t8..10 = part
        } else           v = red[0][q-4] + red[1][q-4] + red[2][q-4] + red[3][q-4];
        atomicAdd(&ev[b * 16 + q], v);
    }
}

// ---------------- kernel 4: head + log_softmax ----------------
__global__ __launch_bounds__(128) void head_kernel(const float* __restrict__ ev,
                                                   const float* __restrict__ fcw,
                                                   const float* __restrict__ fcb,
                                                   float* __restrict__ out) {
    int b = threadIdx.x;
    if (b >= 128) return;
    float e[16];
    #pragma unroll
    for (int q = 0; q < 16; ++q) e[q] = ev[b * 16 + q];
    float lg[16];
    float mx = -1e30f;
    #pragma unroll
    for (int c = 0; c < 16; ++c) {
        float v = fcb[c];
        #pragma unroll
        for (int q = 0; q < 16; ++q) v += e[q] * fcw[c * 16 + q];
        lg[c] = v;
        mx = fmaxf(mx, v);
    }
    float se = 0.f;
    #pragma unroll
    for (int c = 0; c < 16; ++c) se += expf(lg[c] - mx);
    float lse = mx + logf(se);
    #pragma unroll
    for (int c = 0; c < 16; ++c) out[b * 16 + c] = lg[c] - lse;
}

// ---------------- launch ----------------
extern "C" void kernel_launch(void* const* d_in, const int* in_sizes, int n_in,
                              void* d_out, int out_size, void* d_ws, size_t ws_size,
                              hipStream_t stream) {
    const float* x    = (const float*)d_in[0];
    const float* cw   = (const float*)d_in[1];
    const float* cb   = (const float*)d_in[2];
    const float* rot1 = (const float*)d_in[3];
    const float* crx1 = (const float*)d_in[4];
    const float* rot2 = (const float*)d_in[5];
    const float* crx2 = (const float*)d_in[6];
    const float* fcw  = (const float*)d_in[7];
    const float* fcb  = (const float*)d_in[8];

    float* ws    = (float*)d_ws;
    float* p     = ws;                     // 4096 floats
    float* crxcs = ws + 4096;              // 64
    float* ev    = ws + 8192;              // 2048
    float* rvg   = ws + 16384;             // 128*2*4*32*2 = 65536 -> ends 81920
    f2* Aout     = (f2*)(ws + 81920);      // 128*4*2048 f2 = 8 MiB

    pool_kernel<<<4096, 256, 0, stream>>>(x, p);
    qfused<<<256, 256, 0, stream>>>(p, cw, cb, rot1, crx1, rot2, crx2,
                                    crxcs, ev, rvg, Aout);
    qev<<<1024, 256, 0, stream>>>(crxcs, rvg, Aout, ev);
    head_kernel<<<1, 128, 0, stream>>>(ev, fcw, fcb, (float*)d_out);
}